// Round 14
// baseline (288.886 us; speedup 1.0000x reference)
//
#include <hip/hip_runtime.h>
#include <stdint.h>
#include <math.h>

typedef unsigned int u32;

#define BB 4096
#define DD 256
#define KK 512
#define LL 32768
#define QQ 8192

// ---------------- Threefry2x32 (JAX-exact, 20 rounds) ----------------
__host__ __device__ inline void tf2x32(u32 k0, u32 k1, u32 c0, u32 c1, u32& o0, u32& o1) {
  u32 ks2 = k0 ^ k1 ^ 0x1BD11BDAu;
  u32 x0 = c0 + k0, x1 = c1 + k1;
#define TF_R(r) { x0 += x1; x1 = ((x1 << (r)) | (x1 >> (32 - (r)))); x1 ^= x0; }
  TF_R(13) TF_R(15) TF_R(26) TF_R(6)
  x0 += k1; x1 += ks2 + 1u;
  TF_R(17) TF_R(29) TF_R(16) TF_R(24)
  x0 += ks2; x1 += k0 + 2u;
  TF_R(13) TF_R(15) TF_R(26) TF_R(6)
  x0 += k0; x1 += k1 + 3u;
  TF_R(17) TF_R(29) TF_R(16) TF_R(24)
  x0 += k1; x1 += ks2 + 4u;
  TF_R(13) TF_R(15) TF_R(26) TF_R(6)
  x0 += ks2; x1 += k0 + 5u;
#undef TF_R
  o0 = x0; o1 = x1;
}

__device__ inline u32 rbits32(u32 k0, u32 k1, u32 i) {
  u32 a, b;
  tf2x32(k0, k1, 0u, i, a, b);
  return a ^ b;
}

__device__ inline float u01f(u32 bits) {
  return __uint_as_float(0x3f800000u | (bits >> 9)) - 1.0f;
}

// f64-log gumbel: argmax-critical path only (bit-stable vs CPU libm)
__device__ inline float gumbel_at(u32 k0, u32 k1, u32 i) {
  float f = u01f(rbits32(k0, k1, i));
  float u = fmaxf(1e-20f, f + 1e-20f);
  float l1 = (float)log((double)u);
  float l2 = (float)log((double)(-l1));
  return -l2;
}

// fast f32 gumbel: continuous-output paths (y1 softmax)
__device__ inline float gumbel_f32(u32 k0, u32 k1, u32 i) {
  float f = u01f(rbits32(k0, k1, i));
  float u = fmaxf(1e-20f, f + 1e-20f);
  float l1 = __logf(u);
  return -__logf(-l1);
}

// XLA f32 ErfInv (Giles polynomial)
__device__ inline float erfinv32(float x) {
  float w = -log1pf(-x * x);
  float p;
  if (w < 5.0f) {
    w -= 2.5f;
    p = 2.81022636e-08f;
    p = fmaf(p, w, 3.43273939e-07f);
    p = fmaf(p, w, -3.5233877e-06f);
    p = fmaf(p, w, -4.39150654e-06f);
    p = fmaf(p, w, 0.00021858087f);
    p = fmaf(p, w, -0.00125372503f);
    p = fmaf(p, w, -0.00417768164f);
    p = fmaf(p, w, 0.246640727f);
    p = fmaf(p, w, 1.50140941f);
  } else {
    w = sqrtf(w) - 3.0f;
    p = -0.000200214257f;
    p = fmaf(p, w, 0.000100950558f);
    p = fmaf(p, w, 0.00134934322f);
    p = fmaf(p, w, -0.00367342844f);
    p = fmaf(p, w, 0.00573950773f);
    p = fmaf(p, w, -0.0076224613f);
    p = fmaf(p, w, 0.00943887047f);
    p = fmaf(p, w, 1.00167406f);
    p = fmaf(p, w, 2.83297682f);
  }
  return p * x;
}

// ---------------- queue_k raw sumsq (for sk) ----------------
__global__ __launch_bounds__(256)
void k_sumsq(const float* __restrict__ x, int n, float* __restrict__ partial) {
  __shared__ float sm[256];
  float s = 0.0f;
  for (int i = blockIdx.x * 256 + threadIdx.x; i < n; i += gridDim.x * 256) {
    float v = x[i]; s = fmaf(v, v, s);
  }
  sm[threadIdx.x] = s; __syncthreads();
  for (int off = 128; off > 0; off >>= 1) {
    if (threadIdx.x < off) sm[threadIdx.x] += sm[threadIdx.x + off];
    __syncthreads();
  }
  if (threadIdx.x == 0) partial[blockIdx.x] = sm[0];
}

// ---------------- fused stats: z=0 queue_n (64 rows/blk), z=1 constructed queue (16 rows/blk)
__global__ __launch_bounds__(256)
void k_stats(const float* __restrict__ qn, const float* __restrict__ qk_in,
             const float* __restrict__ partK,
             float* __restrict__ colpart, float* __restrict__ sqpart,
             u32 kqa, u32 kqb) {
  __shared__ float smc[4][256];
  __shared__ float sm[256];
  int tid = threadIdx.x, g = tid >> 6, l = tid & 63;
  int z = blockIdx.y;
  float4 ca = {0.f, 0.f, 0.f, 0.f};
  float ss = 0.0f;
  if (z == 0) {
    int base = blockIdx.x * 64;
    for (int j = base + g; j < base + 64; j += 4) {
      float4 v = *(const float4*)(qn + (size_t)j * 256 + l * 4);
      ca.x += v.x; ca.y += v.y; ca.z += v.z; ca.w += v.w;
      ss = fmaf(v.x, v.x, ss); ss = fmaf(v.y, v.y, ss);
      ss = fmaf(v.z, v.z, ss); ss = fmaf(v.w, v.w, ss);
    }
  } else {
    sm[tid] = partK[tid]; __syncthreads();
    for (int off = 128; off > 0; off >>= 1) {
      if (tid < off) sm[tid] += sm[tid + off];
      __syncthreads();
    }
    float sk = (float)(1.0 / sqrt((double)fmaxf(sm[0], 1e-12f)));
    __syncthreads();
    const float lo = -0.99999994f;
    int base = blockIdx.x * 16;
    for (int j = base + g; j < base + 16; j += 4) {
      int i0 = j * 256 + l * 4;
      float4 v = *(const float4*)(qk_in + i0);
      float vin[4] = {v.x, v.y, v.z, v.w};
      float valv[4];
#pragma unroll
      for (int e = 0; e < 4; e++) {
        float qk = vin[e] * sk;
        float f = u01f(rbits32(kqa, kqb, (u32)(i0 + e)));
        float u = fmaxf(lo, f * 2.0f + lo);
        float nv = 1.41421354f * erfinv32(u);
        float t = qk + 0.1f * nv;
        valv[e] = t + qk;
        ss = fmaf(valv[e], valv[e], ss);
      }
      ca.x += valv[0]; ca.y += valv[1]; ca.z += valv[2]; ca.w += valv[3];
    }
  }
  smc[g][l * 4 + 0] = ca.x; smc[g][l * 4 + 1] = ca.y;
  smc[g][l * 4 + 2] = ca.z; smc[g][l * 4 + 3] = ca.w;
  sm[tid] = ss; __syncthreads();
  colpart[(size_t)z * 131072 + blockIdx.x * 256 + tid] =
      (smc[0][tid] + smc[1][tid]) + (smc[2][tid] + smc[3][tid]);
  for (int off = 128; off > 0; off >>= 1) {
    if (tid < off) sm[tid] += sm[tid + off];
    __syncthreads();
  }
  if (tid == 0) sqpart[z * 512 + blockIdx.x] = sm[0];
}

// parallel finalize csum: grid (256, 2)
__global__ __launch_bounds__(256)
void k_finalize_csum(const float* __restrict__ colpart, float* __restrict__ csum) {
  __shared__ float sm[256];
  int d = blockIdx.x, z = blockIdx.y, t = threadIdx.x;
  const float* cp = colpart + (size_t)z * 131072;
  float a = cp[(size_t)t * 256 + d] + cp[(size_t)(t + 256) * 256 + d];
  sm[t] = a; __syncthreads();
  for (int off = 128; off > 0; off >>= 1) {
    if (t < off) sm[t] += sm[t + off];
    __syncthreads();
  }
  if (t == 0) csum[z * 256 + d] = sm[0];
}

// grid 2: lsc[z] = rsqrt(sum(sqpart[z]))/0.07
__global__ __launch_bounds__(256)
void k_finalize_lsc(const float* __restrict__ sqpart, float* __restrict__ lscOut) {
  __shared__ float sm[256];
  int t = threadIdx.x, z = blockIdx.x;
  const float* sq = sqpart + z * 512;
  float a = sq[t] + sq[t + 256];
  sm[t] = a; __syncthreads();
  for (int off = 128; off > 0; off >>= 1) {
    if (t < off) sm[t] += sm[t + off];
    __syncthreads();
  }
  if (t == 0) {
    float sr = (float)(1.0 / sqrt((double)fmaxf(sm[0], 1e-12f)));
    lscOut[z] = sr / 0.07f;
  }
}

// ---------------- f32 GEMMs: 128Mx64N tile, 8x4 register tile ----------------
// K-inner order (kt 16-step, kx 0..15) identical to the 64x64 version ->
// outputs bitwise identical (argmax path safe).
__global__ __launch_bounds__(256)
void k_gemm_nt(const float* __restrict__ A0, const float* __restrict__ A1,
               const float* __restrict__ B0, const float* __restrict__ B1,
               float* __restrict__ C, int N) {
  __shared__ float As[16][132], Bs[16][68];
  int tid = threadIdx.x;
  int tx = tid & 15, ty = tid >> 4;
  int rowBase = blockIdx.y * 128, colBase = blockIdx.x * 64;
  int br = blockIdx.z;
  const float* A = br ? A1 : A0;
  const float* Bm = br ? B1 : B0;
  float* Cd = C + (size_t)br * BB * KK;
  float c[8][4] = {};
  for (int kt = 0; kt < 256; kt += 16) {
#pragma unroll
    for (int q = 0; q < 8; q++) {
      int idx = tid + 256 * q;
      int kkx = idx & 15, rr = idx >> 4;
      As[kkx][rr] = A[(size_t)(rowBase + rr) * 256 + kt + kkx];
    }
#pragma unroll
    for (int q = 0; q < 4; q++) {
      int idx = tid + 256 * q;
      int kkx = idx & 15, rr = idx >> 4;
      Bs[kkx][rr] = Bm[(size_t)(colBase + rr) * 256 + kt + kkx];
    }
    __syncthreads();
#pragma unroll
    for (int kx = 0; kx < 16; kx++) {
      float4 a0 = *(const float4*)&As[kx][ty * 8];
      float4 a1 = *(const float4*)&As[kx][ty * 8 + 4];
      float4 b4 = *(const float4*)&Bs[kx][tx * 4];
      float av[8] = {a0.x, a0.y, a0.z, a0.w, a1.x, a1.y, a1.z, a1.w};
      float bv[4] = {b4.x, b4.y, b4.z, b4.w};
#pragma unroll
      for (int r = 0; r < 8; r++)
#pragma unroll
        for (int q = 0; q < 4; q++)
          c[r][q] = fmaf(av[r], bv[q], c[r][q]);
    }
    __syncthreads();
  }
#pragma unroll
  for (int r = 0; r < 8; r++)
#pragma unroll
    for (int q = 0; q < 4; q++)
      Cd[(size_t)(rowBase + ty * 8 + r) * N + colBase + tx * 4 + q] = c[r][q];
}

// agg_n = Y @ ctx (NN), 128x64 tile; grid (DD/64, BB/128, 2); sumsq partials
__global__ __launch_bounds__(256)
void k_gemm_aggn(const float* __restrict__ Yb, const float* __restrict__ B0,
                 const float* __restrict__ B1, float* __restrict__ D0,
                 float* __restrict__ D1, float* __restrict__ sqp) {
  __shared__ float As[16][132], Bs[16][68];
  __shared__ float sq[256];
  int tid = threadIdx.x;
  int tx = tid & 15, ty = tid >> 4;
  int rowBase = blockIdx.y * 128, colBase = blockIdx.x * 64;
  int br = blockIdx.z;
  const float* A = Yb + (size_t)br * BB * KK;
  const float* Bm = br ? B1 : B0;
  float* dst = br ? D1 : D0;
  float c[8][4] = {};
  for (int kt = 0; kt < KK; kt += 16) {
#pragma unroll
    for (int q = 0; q < 8; q++) {
      int idx = tid + 256 * q;
      int kkx = idx & 15, rr = idx >> 4;
      As[kkx][rr] = A[(size_t)(rowBase + rr) * KK + kt + kkx];
    }
#pragma unroll
    for (int q = 0; q < 4; q++) {
      int kk = (tid >> 6) * 4 + q;
      int jj = tid & 63;
      Bs[kk][jj] = Bm[(size_t)(kt + kk) * DD + colBase + jj];
    }
    __syncthreads();
#pragma unroll
    for (int kx = 0; kx < 16; kx++) {
      float4 a0 = *(const float4*)&As[kx][ty * 8];
      float4 a1 = *(const float4*)&As[kx][ty * 8 + 4];
      float4 b4 = *(const float4*)&Bs[kx][tx * 4];
      float av[8] = {a0.x, a0.y, a0.z, a0.w, a1.x, a1.y, a1.z, a1.w};
      float bv[4] = {b4.x, b4.y, b4.z, b4.w};
#pragma unroll
      for (int r = 0; r < 8; r++)
#pragma unroll
        for (int q = 0; q < 4; q++)
          c[r][q] = fmaf(av[r], bv[q], c[r][q]);
    }
    __syncthreads();
  }
#pragma unroll
  for (int r = 0; r < 8; r++)
#pragma unroll
    for (int q = 0; q < 4; q++)
      dst[(size_t)(rowBase + ty * 8 + r) * DD + colBase + tx * 4 + q] = c[r][q];
  float ls = 0.0f;
#pragma unroll
  for (int r = 0; r < 8; r++)
#pragma unroll
    for (int q = 0; q < 4; q++) ls = fmaf(c[r][q], c[r][q], ls);
  sq[tid] = ls; __syncthreads();
  for (int off = 128; off > 0; off >>= 1) {
    if (tid < off) sq[tid] += sq[tid + off];
    __syncthreads();
  }
  if (tid == 0) sqp[br * 128 + blockIdx.y * gridDim.x + blockIdx.x] = sq[0];
}

// agg_k partials = BIN @ feat (NN), split-K, 128x64 tile; grid (DD/64, KK/128, 16)
__global__ __launch_bounds__(256)
void k_gemm_aggk(const float* __restrict__ BIN, const float* __restrict__ B0,
                 const float* __restrict__ B1, float* __restrict__ CP) {
  __shared__ float As[16][132], Bs[16][68];
  int tid = threadIdx.x;
  int tx = tid & 15, ty = tid >> 4;
  int rowBase = blockIdx.y * 128, colBase = blockIdx.x * 64;
  int br = blockIdx.z >> 3, s = blockIdx.z & 7;
  const float* A = BIN + (size_t)br * KK * BB;
  const float* Bm = br ? B1 : B0;
  int k0 = s * 512;
  float c[8][4] = {};
  for (int kt = k0; kt < k0 + 512; kt += 16) {
#pragma unroll
    for (int q = 0; q < 8; q++) {
      int idx = tid + 256 * q;
      int kkx = idx & 15, rr = idx >> 4;
      As[kkx][rr] = A[(size_t)(rowBase + rr) * BB + kt + kkx];
    }
#pragma unroll
    for (int q = 0; q < 4; q++) {
      int kk = (tid >> 6) * 4 + q;
      int jj = tid & 63;
      Bs[kk][jj] = Bm[(size_t)(kt + kk) * DD + colBase + jj];
    }
    __syncthreads();
#pragma unroll
    for (int kx = 0; kx < 16; kx++) {
      float4 a0 = *(const float4*)&As[kx][ty * 8];
      float4 a1 = *(const float4*)&As[kx][ty * 8 + 4];
      float4 b4 = *(const float4*)&Bs[kx][tx * 4];
      float av[8] = {a0.x, a0.y, a0.z, a0.w, a1.x, a1.y, a1.z, a1.w};
      float bv[4] = {b4.x, b4.y, b4.z, b4.w};
#pragma unroll
      for (int r = 0; r < 8; r++)
#pragma unroll
        for (int q = 0; q < 4; q++)
          c[r][q] = fmaf(av[r], bv[q], c[r][q]);
    }
    __syncthreads();
  }
  float* dst = CP + (size_t)blockIdx.z * KK * DD;
#pragma unroll
  for (int r = 0; r < 8; r++)
#pragma unroll
    for (int q = 0; q < 4; q++)
      dst[(size_t)(rowBase + ty * 8 + r) * DD + colBase + tx * 4 + q] = c[r][q];
}

// sum split-K partials, divide by row-sum, emit sumsq partials; grid (512, 2)
__global__ __launch_bounds__(256)
void k_reduce_div(const float* __restrict__ CP, const float* __restrict__ rs2,
                  float* __restrict__ D0, float* __restrict__ D1,
                  float* __restrict__ sqp) {
  __shared__ float sq[256];
  int tid = threadIdx.x, br = blockIdx.y;
  int i = blockIdx.x * 256 + tid;
  const int MN = KK * DD;
  const float* cp = CP + (size_t)br * 8 * MN;
  float s = 0.0f;
  for (int t = 0; t < 8; t++) s += cp[(size_t)t * MN + i];
  float v = s / (rs2[br * KK + (i >> 8)] + 1e-8f);
  float* dst = br ? D1 : D0;
  dst[i] = v;
  sq[tid] = v * v; __syncthreads();
  for (int off = 128; off > 0; off >>= 1) {
    if (tid < off) sq[tid] += sq[tid + off];
    __syncthreads();
  }
  if (tid == 0) sqp[br * 512 + blockIdx.x] = sq[0];
}

// reduce sumsq partials -> rsqrt; scale in place; grid (nblk, 2)
__global__ __launch_bounds__(256)
void k_scale_cvt(float* __restrict__ D0, float* __restrict__ D1,
                 const float* __restrict__ sqp, int np, int n) {
  __shared__ float sm[256];
  int tid = threadIdx.x, br = blockIdx.y;
  const float* sq = sqp + br * np;
  float a = 0.0f;
  for (int i = tid; i < np; i += 256) a += sq[i];
  sm[tid] = a; __syncthreads();
  for (int off = 128; off > 0; off >>= 1) {
    if (tid < off) sm[tid] += sm[tid + off];
    __syncthreads();
  }
  float f = (float)(1.0 / sqrt((double)fmaxf(sm[0], 1e-12f)));
  float* data = br ? D1 : D0;
  int i = (blockIdx.x * 256 + tid) * 4;
  if (i < n) {
    float4 v = *(const float4*)(data + i);
    v.x *= f; v.y *= f; v.z *= f; v.w *= f;
    *(float4*)(data + i) = v;
  }
}

// ---------------- softmax(y1) + hard argmax(y2), batched over branches ----------------
__global__ __launch_bounds__(256)
void k_softmax_assign(const float* __restrict__ T, float* __restrict__ Y,
                      float* __restrict__ assignOut,
                      u32 g1a0, u32 g1b0, u32 g1a1, u32 g1b1, u32 g2a, u32 g2b) {
  __shared__ float smA[4], smS[4], smM2[4], smS2[4], smV[4];
  __shared__ int smI[4];
  int bid = blockIdx.x, tid = threadIdx.x;
  int br = bid >> 12, b = bid & 4095;
  u32 g1a = br ? g1a1 : g1a0, g1b = br ? g1b1 : g1b0;
  const float* knT = T + (size_t)br * BB * KK;
  float* Yd = Y + (size_t)br * BB * KK;
  int lane = tid & 63, wid = tid >> 6;
  int i0 = b * KK + tid, i1 = i0 + 256;
  float x0 = knT[i0], x1 = knT[i1];

  float z0 = x0 + gumbel_f32(g1a, g1b, (u32)i0);
  float z1 = x1 + gumbel_f32(g1a, g1b, (u32)i1);
  float wm = fmaxf(z0, z1);
#pragma unroll
  for (int off = 1; off < 64; off <<= 1) wm = fmaxf(wm, __shfl_xor(wm, off, 64));
  if (lane == 0) smA[wid] = wm;
  __syncthreads();
  float m = fmaxf(fmaxf(smA[0], smA[1]), fmaxf(smA[2], smA[3]));
  float e0 = expf(z0 - m), e1 = expf(z1 - m);
  float ws = e0 + e1;
#pragma unroll
  for (int off = 1; off < 64; off <<= 1) ws += __shfl_xor(ws, off, 64);
  if (lane == 0) smS[wid] = ws;
  __syncthreads();
  float s = (smS[0] + smS[1]) + (smS[2] + smS[3]);
  Yd[i0] = e0 / s;
  Yd[i1] = e1 / s;

  if (br == 0) {
    float w0 = x0 + gumbel_at(g2a, g2b, (u32)i0);
    float w1 = x1 + gumbel_at(g2a, g2b, (u32)i1);
    float wm2 = fmaxf(w0, w1);
#pragma unroll
    for (int off = 1; off < 64; off <<= 1) wm2 = fmaxf(wm2, __shfl_xor(wm2, off, 64));
    if (lane == 0) smM2[wid] = wm2;
    __syncthreads();
    float m2 = fmaxf(fmaxf(smM2[0], smM2[1]), fmaxf(smM2[2], smM2[3]));
    float f0 = expf(w0 - m2), f1 = expf(w1 - m2);
    float ws2 = f0 + f1;
#pragma unroll
    for (int off = 1; off < 64; off <<= 1) ws2 += __shfl_xor(ws2, off, 64);
    if (lane == 0) smS2[wid] = ws2;
    __syncthreads();
    float s2 = (smS2[0] + smS2[1]) + (smS2[2] + smS2[3]);
    float y0 = f0 / s2, y1v = f1 / s2;
    float bv; int bi;
    if (y1v > y0) { bv = y1v; bi = tid + 256; } else { bv = y0; bi = tid; }
#pragma unroll
    for (int off = 1; off < 64; off <<= 1) {
      float ov = __shfl_xor(bv, off, 64);
      int oi = __shfl_xor(bi, off, 64);
      if (ov > bv || (ov == bv && oi < bi)) { bv = ov; bi = oi; }
    }
    if (lane == 0) { smV[wid] = bv; smI[wid] = bi; }
    __syncthreads();
    if (tid == 0) {
      float cv = smV[0]; int ci = smI[0];
#pragma unroll
      for (int t = 1; t < 4; t++) {
        if (smV[t] > cv || (smV[t] == cv && smI[t] < ci)) { cv = smV[t]; ci = smI[t]; }
      }
      assignOut[b] = (float)ci;
    }
  }
}

// ---------------- stochastic binary, 64b x 32k tiles, grid 2048 (8 blk/CU) ----------------
__global__ __launch_bounds__(256)
void k_binary(const float* __restrict__ T, float* __restrict__ BIN,
              float* __restrict__ rs2,
              u32 k3a0, u32 k3b0, u32 k3a1, u32 k3b1) {
  __shared__ float lds[64][33];
  int tid = threadIdx.x;
  int bid = blockIdx.x;
  int br = bid >> 10, t = bid & 1023;
  u32 k3a = br ? k3a1 : k3a0, k3b = br ? k3b1 : k3b0;
  const float* Tb = T + (size_t)br * BB * KK;
  float* Bd = BIN + (size_t)br * KK * BB;
  float* rs = rs2 + br * KK;
  int b0 = (t & 63) * 64;
  int k0 = (t >> 6) * 32;
  int cl32 = tid & 31, rl8 = tid >> 5;
  for (int bb = rl8; bb < 64; bb += 8)
    lds[bb][cl32] = Tb[(size_t)(b0 + bb) * KK + k0 + cl32];
  __syncthreads();
  int l = tid & 63, g = tid >> 6;
  for (int kk = g; kk < 32; kk += 4) {
    int k = k0 + kk, b = b0 + l;
    float x = lds[l][kk];
    float prob = 1.0f / (1.0f + expf(-x));
    u32 i = (u32)(k * BB + b);
    float eps = u01f(rbits32(k3a, k3b, i));
    float bin = (prob > eps) ? 1.0f : 0.0f;
    Bd[(size_t)k * BB + b] = bin;
    float srow = bin;
#pragma unroll
    for (int off = 1; off < 64; off <<= 1) srow += __shfl_xor(srow, off, 64);
    if (l == 0) atomicAdd(rs + k, srow);
  }
}

// ---------------- Taylor-collapsed InfoNCE loss, batched (1152 blocks) ----------------
__global__ __launch_bounds__(256)
void k_loss_row(const float* __restrict__ QN, const float* __restrict__ KPN,
                const float* __restrict__ QK, const float* __restrict__ KPK,
                const float* __restrict__ csum, const float* __restrict__ lscp,
                float* __restrict__ LPN, float* __restrict__ LPK) {
  __shared__ float pt[4];
  int w = threadIdx.x >> 6, l = threadIdx.x & 63;
  int bid = blockIdx.x;
  int isK = (bid >= 1024);
  int rb = isK ? (bid - 1024) : bid;
  const float* Q  = isK ? QK : QN;
  const float* KP = isK ? KPK : KPN;
  const float* cs4 = csum + (isK ? 256 : 0);
  float Lc = isK ? (float)QQ : (float)LL;
  float lsc = lscp[isK ? 1 : 0];
  int r = rb * 4 + w;
  float4 q = *(const float4*)(Q + (size_t)r * 256 + l * 4);
  float4 kp = *(const float4*)(KP + (size_t)r * 256 + l * 4);
  float4 cs = *(const float4*)(cs4 + l * 4);
  float d1 = q.x * kp.x + q.y * kp.y + q.z * kp.z + q.w * kp.w;
  float d2 = q.x * cs.x + q.y * cs.y + q.z * cs.z + q.w * cs.w;
#pragma unroll
  for (int off = 1; off < 64; off <<= 1) {
    d1 += __shfl_xor(d1, off, 64);
    d2 += __shfl_xor(d2, off, 64);
  }
  if (l == 0) {
    float z0 = d1 / 0.07f;
    double S = (double)Lc + (double)expf(z0) + (double)(lsc * d2);
    pt[w] = (float)(log(S)) - z0;
  }
  __syncthreads();
  if (threadIdx.x == 0) {
    float v = (pt[0] + pt[1]) + (pt[2] + pt[3]);
    if (isK) LPK[rb] = v; else LPN[rb] = v;
  }
}

__global__ __launch_bounds__(256)
void k_loss_final(const float* __restrict__ LPN, int nN, float invMN,
                  const float* __restrict__ LPK, int nK, float invMK,
                  float* __restrict__ outLoss) {
  __shared__ float sm[256];
  int tid = threadIdx.x;
  float a = 0.0f;
  for (int i = tid; i < nN; i += 256) a += LPN[i];
  sm[tid] = a; __syncthreads();
  for (int off = 128; off > 0; off >>= 1) {
    if (tid < off) sm[tid] += sm[tid + off];
    __syncthreads();
  }
  float lossN = sm[0] * invMN;
  __syncthreads();
  float b = 0.0f;
  for (int i = tid; i < nK; i += 256) b += LPK[i];
  sm[tid] = b; __syncthreads();
  for (int off = 128; off > 0; off >>= 1) {
    if (tid < off) sm[tid] += sm[tid + off];
    __syncthreads();
  }
  if (tid == 0) outLoss[0] = lossN + sm[0] * invMK;
}

// ---------------- launch ----------------
extern "C" void kernel_launch(void* const* d_in, const int* in_sizes, int n_in,
                              void* d_out, int out_size, void* d_ws, size_t ws_size,
                              hipStream_t stream) {
  const float* feat0 = (const float*)d_in[0];
  const float* feat1 = (const float*)d_in[1];
  const float* ctx0  = (const float*)d_in[2];
  const float* ctx1  = (const float*)d_in[3];
  const float* queue_n = (const float*)d_in[4];
  const float* queue_k = (const float*)d_in[5];

  float* W = (float*)d_ws;
  size_t o = 0;
  float* T     = W + o; o += 2 * (size_t)BB * KK;
  float* Yb    = W + o; o += 2 * (size_t)BB * KK;
  float* BIN   = W + o; o += 2 * (size_t)KK * BB;
  float* CP    = W + o; o += 16 * (size_t)KK * DD;
  float* AGGN1 = W + o; o += (size_t)BB * DD;
  float* AGGK1 = W + o; o += (size_t)KK * DD;
  float* RS2   = W + o; o += 2 * KK;
  float* CPS   = W + o; o += 2 * 131072;
  float* SQ2   = W + o; o += 2 * 512;
  float* CS    = W + o; o += 2 * 256;
  float* LSC   = W + o; o += 2;
  float* LPN   = W + o; o += 1024;
  float* LPK   = W + o; o += 128;
  float* PART_K = W + o; o += 256;
  float* SQPN  = W + o; o += 2 * 128;
  float* SQPK  = W + o; o += 2 * 512;

  float* out = (float*)d_out;
  float* outAssign = out;
  float* outAggn2  = out + BB;
  float* outAggk2  = out + BB + (size_t)BB * DD;
  float* outLoss   = out + BB + (size_t)BB * DD + (size_t)KK * DD;

  u32 kq0, kq1, kc[2][2];
  tf2x32(0u, 42u, 0u, 0u, kq0, kq1);
  tf2x32(0u, 42u, 0u, 1u, kc[0][0], kc[0][1]);
  tf2x32(0u, 42u, 0u, 2u, kc[1][0], kc[1][1]);
  u32 sub[2][3][2];
  for (int br = 0; br < 2; br++)
    for (int t = 0; t < 3; t++)
      tf2x32(kc[br][0], kc[br][1], 0u, (u32)t, sub[br][t][0], sub[br][t][1]);

  // stats chain
  k_sumsq<<<256, 256, 0, stream>>>(queue_k, QQ * DD, PART_K);
  k_stats<<<dim3(512, 2), 256, 0, stream>>>(queue_n, queue_k, PART_K, CPS, SQ2, kq0, kq1);
  k_finalize_csum<<<dim3(256, 2), 256, 0, stream>>>(CPS, CS);
  k_finalize_lsc<<<2, 256, 0, stream>>>(SQ2, LSC);

  hipMemsetAsync(RS2, 0, 2 * KK * sizeof(float), stream);

  // batched branch pipeline
  k_gemm_nt<<<dim3(KK / 64, BB / 128, 2), 256, 0, stream>>>(feat0, feat1, ctx0, ctx1, T, KK);
  k_softmax_assign<<<2 * BB, 256, 0, stream>>>(T, Yb, outAssign,
      sub[0][0][0], sub[0][0][1], sub[1][0][0], sub[1][0][1], sub[0][1][0], sub[0][1][1]);
  k_binary<<<2048, 256, 0, stream>>>(T, BIN, RS2,
      sub[0][2][0], sub[0][2][1], sub[1][2][0], sub[1][2][1]);
  k_gemm_aggn<<<dim3(DD / 64, BB / 128, 2), 256, 0, stream>>>(Yb, ctx0, ctx1, AGGN1, outAggn2, SQPN);
  k_gemm_aggk<<<dim3(DD / 64, KK / 128, 16), 256, 0, stream>>>(BIN, feat0, feat1, CP);
  k_reduce_div<<<dim3(KK * DD / 256, 2), 256, 0, stream>>>(CP, RS2, AGGK1, outAggk2, SQPK);
  k_scale_cvt<<<dim3(BB * DD / 1024, 2), 256, 0, stream>>>(AGGN1, outAggn2, SQPN, 128, BB * DD);
  k_scale_cvt<<<dim3(KK * DD / 1024, 2), 256, 0, stream>>>(AGGK1, outAggk2, SQPK, 512, KK * DD);

  // Taylor-collapsed losses (batched rows: 1024 n-blocks + 128 k-blocks)
  k_loss_row<<<1152, 256, 0, stream>>>(AGGN1, outAggn2, AGGK1, outAggk2, CS, LSC, LPN, LPK);
  k_loss_final<<<1, 256, 0, stream>>>(LPN, BB / 4, 1.0f / BB, LPK, KK / 4, 1.0f / KK, outLoss);
}

// Round 15
// 250.512 us; speedup vs baseline: 1.1532x; 1.1532x over previous
//
#include <hip/hip_runtime.h>
#include <stdint.h>
#include <math.h>

typedef unsigned int u32;

#define BB 4096
#define DD 256
#define KK 512
#define LL 32768
#define QQ 8192

// ---------------- Threefry2x32 (JAX-exact, 20 rounds) ----------------
__host__ __device__ inline void tf2x32(u32 k0, u32 k1, u32 c0, u32 c1, u32& o0, u32& o1) {
  u32 ks2 = k0 ^ k1 ^ 0x1BD11BDAu;
  u32 x0 = c0 + k0, x1 = c1 + k1;
#define TF_R(r) { x0 += x1; x1 = ((x1 << (r)) | (x1 >> (32 - (r)))); x1 ^= x0; }
  TF_R(13) TF_R(15) TF_R(26) TF_R(6)
  x0 += k1; x1 += ks2 + 1u;
  TF_R(17) TF_R(29) TF_R(16) TF_R(24)
  x0 += ks2; x1 += k0 + 2u;
  TF_R(13) TF_R(15) TF_R(26) TF_R(6)
  x0 += k0; x1 += k1 + 3u;
  TF_R(17) TF_R(29) TF_R(16) TF_R(24)
  x0 += k1; x1 += ks2 + 4u;
  TF_R(13) TF_R(15) TF_R(26) TF_R(6)
  x0 += ks2; x1 += k0 + 5u;
#undef TF_R
  o0 = x0; o1 = x1;
}

__device__ inline u32 rbits32(u32 k0, u32 k1, u32 i) {
  u32 a, b;
  tf2x32(k0, k1, 0u, i, a, b);
  return a ^ b;
}

__device__ inline float u01f(u32 bits) {
  return __uint_as_float(0x3f800000u | (bits >> 9)) - 1.0f;
}

// f64-log gumbel: argmax-critical path only (bit-stable vs CPU libm)
__device__ inline float gumbel_at(u32 k0, u32 k1, u32 i) {
  float f = u01f(rbits32(k0, k1, i));
  float u = fmaxf(1e-20f, f + 1e-20f);
  float l1 = (float)log((double)u);
  float l2 = (float)log((double)(-l1));
  return -l2;
}

// fast f32 gumbel: continuous-output paths (y1 softmax)
__device__ inline float gumbel_f32(u32 k0, u32 k1, u32 i) {
  float f = u01f(rbits32(k0, k1, i));
  float u = fmaxf(1e-20f, f + 1e-20f);
  float l1 = __logf(u);
  return -__logf(-l1);
}

// XLA f32 ErfInv (Giles polynomial)
__device__ inline float erfinv32(float x) {
  float w = -log1pf(-x * x);
  float p;
  if (w < 5.0f) {
    w -= 2.5f;
    p = 2.81022636e-08f;
    p = fmaf(p, w, 3.43273939e-07f);
    p = fmaf(p, w, -3.5233877e-06f);
    p = fmaf(p, w, -4.39150654e-06f);
    p = fmaf(p, w, 0.00021858087f);
    p = fmaf(p, w, -0.00125372503f);
    p = fmaf(p, w, -0.00417768164f);
    p = fmaf(p, w, 0.246640727f);
    p = fmaf(p, w, 1.50140941f);
  } else {
    w = sqrtf(w) - 3.0f;
    p = -0.000200214257f;
    p = fmaf(p, w, 0.000100950558f);
    p = fmaf(p, w, 0.00134934322f);
    p = fmaf(p, w, -0.00367342844f);
    p = fmaf(p, w, 0.00573950773f);
    p = fmaf(p, w, -0.0076224613f);
    p = fmaf(p, w, 0.00943887047f);
    p = fmaf(p, w, 1.00167406f);
    p = fmaf(p, w, 2.83297682f);
  }
  return p * x;
}

// ---------------- queue_k raw sumsq (for sk) ----------------
__global__ __launch_bounds__(256)
void k_sumsq(const float* __restrict__ x, int n, float* __restrict__ partial) {
  __shared__ float sm[256];
  float s = 0.0f;
  for (int i = blockIdx.x * 256 + threadIdx.x; i < n; i += gridDim.x * 256) {
    float v = x[i]; s = fmaf(v, v, s);
  }
  sm[threadIdx.x] = s; __syncthreads();
  for (int off = 128; off > 0; off >>= 1) {
    if (threadIdx.x < off) sm[threadIdx.x] += sm[threadIdx.x + off];
    __syncthreads();
  }
  if (threadIdx.x == 0) partial[blockIdx.x] = sm[0];
}

// ---------------- fused stats: z=0 queue_n (64 rows/blk), z=1 constructed queue (16 rows/blk)
__global__ __launch_bounds__(256)
void k_stats(const float* __restrict__ qn, const float* __restrict__ qk_in,
             const float* __restrict__ partK,
             float* __restrict__ colpart, float* __restrict__ sqpart,
             u32 kqa, u32 kqb) {
  __shared__ float smc[4][256];
  __shared__ float sm[256];
  int tid = threadIdx.x, g = tid >> 6, l = tid & 63;
  int z = blockIdx.y;
  float4 ca = {0.f, 0.f, 0.f, 0.f};
  float ss = 0.0f;
  if (z == 0) {
    int base = blockIdx.x * 64;
    for (int j = base + g; j < base + 64; j += 4) {
      float4 v = *(const float4*)(qn + (size_t)j * 256 + l * 4);
      ca.x += v.x; ca.y += v.y; ca.z += v.z; ca.w += v.w;
      ss = fmaf(v.x, v.x, ss); ss = fmaf(v.y, v.y, ss);
      ss = fmaf(v.z, v.z, ss); ss = fmaf(v.w, v.w, ss);
    }
  } else {
    sm[tid] = partK[tid]; __syncthreads();
    for (int off = 128; off > 0; off >>= 1) {
      if (tid < off) sm[tid] += sm[tid + off];
      __syncthreads();
    }
    float sk = (float)(1.0 / sqrt((double)fmaxf(sm[0], 1e-12f)));
    __syncthreads();
    const float lo = -0.99999994f;
    int base = blockIdx.x * 16;
    for (int j = base + g; j < base + 16; j += 4) {
      int i0 = j * 256 + l * 4;
      float4 v = *(const float4*)(qk_in + i0);
      float vin[4] = {v.x, v.y, v.z, v.w};
      float valv[4];
#pragma unroll
      for (int e = 0; e < 4; e++) {
        float qk = vin[e] * sk;
        float f = u01f(rbits32(kqa, kqb, (u32)(i0 + e)));
        float u = fmaxf(lo, f * 2.0f + lo);
        float nv = 1.41421354f * erfinv32(u);
        float t = qk + 0.1f * nv;
        valv[e] = t + qk;
        ss = fmaf(valv[e], valv[e], ss);
      }
      ca.x += valv[0]; ca.y += valv[1]; ca.z += valv[2]; ca.w += valv[3];
    }
  }
  smc[g][l * 4 + 0] = ca.x; smc[g][l * 4 + 1] = ca.y;
  smc[g][l * 4 + 2] = ca.z; smc[g][l * 4 + 3] = ca.w;
  sm[tid] = ss; __syncthreads();
  colpart[(size_t)z * 131072 + blockIdx.x * 256 + tid] =
      (smc[0][tid] + smc[1][tid]) + (smc[2][tid] + smc[3][tid]);
  for (int off = 128; off > 0; off >>= 1) {
    if (tid < off) sm[tid] += sm[tid + off];
    __syncthreads();
  }
  if (tid == 0) sqpart[z * 512 + blockIdx.x] = sm[0];
}

// parallel finalize csum: grid (256, 2)
__global__ __launch_bounds__(256)
void k_finalize_csum(const float* __restrict__ colpart, float* __restrict__ csum) {
  __shared__ float sm[256];
  int d = blockIdx.x, z = blockIdx.y, t = threadIdx.x;
  const float* cp = colpart + (size_t)z * 131072;
  float a = cp[(size_t)t * 256 + d] + cp[(size_t)(t + 256) * 256 + d];
  sm[t] = a; __syncthreads();
  for (int off = 128; off > 0; off >>= 1) {
    if (t < off) sm[t] += sm[t + off];
    __syncthreads();
  }
  if (t == 0) csum[z * 256 + d] = sm[0];
}

// grid 2: lsc[z] = rsqrt(sum(sqpart[z]))/0.07
__global__ __launch_bounds__(256)
void k_finalize_lsc(const float* __restrict__ sqpart, float* __restrict__ lscOut) {
  __shared__ float sm[256];
  int t = threadIdx.x, z = blockIdx.x;
  const float* sq = sqpart + z * 512;
  float a = sq[t] + sq[t + 256];
  sm[t] = a; __syncthreads();
  for (int off = 128; off > 0; off >>= 1) {
    if (t < off) sm[t] += sm[t + off];
    __syncthreads();
  }
  if (t == 0) {
    float sr = (float)(1.0 / sqrt((double)fmaxf(sm[0], 1e-12f)));
    lscOut[z] = sr / 0.07f;
  }
}

// ---------------- f32 GEMMs: 64x64 tile, 4x4 register tile (proven shape) ----------------
__global__ __launch_bounds__(256)
void k_gemm_nt(const float* __restrict__ A0, const float* __restrict__ A1,
               const float* __restrict__ B0, const float* __restrict__ B1,
               float* __restrict__ C, int N) {
  __shared__ float As[16][68], Bs[16][68];
  int tid = threadIdx.x;
  int tx = tid & 15, ty = tid >> 4;
  int rowBase = blockIdx.y * 64, colBase = blockIdx.x * 64;
  int br = blockIdx.z;
  const float* A = br ? A1 : A0;
  const float* Bm = br ? B1 : B0;
  float* Cd = C + (size_t)br * BB * KK;
  float c[4][4] = {};
  for (int kt = 0; kt < 256; kt += 16) {
#pragma unroll
    for (int q = 0; q < 4; q++) {
      int idx = tid + 256 * q;
      int kkx = idx & 15, rr = idx >> 4;
      As[kkx][rr] = A[(size_t)(rowBase + rr) * 256 + kt + kkx];
      Bs[kkx][rr] = Bm[(size_t)(colBase + rr) * 256 + kt + kkx];
    }
    __syncthreads();
#pragma unroll
    for (int kx = 0; kx < 16; kx++) {
      float4 a4 = *(const float4*)&As[kx][ty * 4];
      float4 b4 = *(const float4*)&Bs[kx][tx * 4];
      float av[4] = {a4.x, a4.y, a4.z, a4.w};
      float bv[4] = {b4.x, b4.y, b4.z, b4.w};
#pragma unroll
      for (int r = 0; r < 4; r++)
#pragma unroll
        for (int q = 0; q < 4; q++)
          c[r][q] = fmaf(av[r], bv[q], c[r][q]);
    }
    __syncthreads();
  }
#pragma unroll
  for (int r = 0; r < 4; r++)
#pragma unroll
    for (int q = 0; q < 4; q++)
      Cd[(size_t)(rowBase + ty * 4 + r) * N + colBase + tx * 4 + q] = c[r][q];
}

// agg_n partials = Y @ ctx (NN), split-K S=2; grid (DD/64, BB/64, 4); z = br*2+s
__global__ __launch_bounds__(256)
void k_gemm_aggn(const float* __restrict__ Yb, const float* __restrict__ B0,
                 const float* __restrict__ B1, float* __restrict__ CPN) {
  __shared__ float As[16][68], Bs[16][68];
  int tid = threadIdx.x;
  int tx = tid & 15, ty = tid >> 4;
  int rowBase = blockIdx.y * 64, colBase = blockIdx.x * 64;
  int br = blockIdx.z >> 1, s = blockIdx.z & 1;
  const float* A = Yb + (size_t)br * BB * KK;
  const float* Bm = br ? B1 : B0;
  int k0 = s * 256;
  float c[4][4] = {};
  for (int kt = k0; kt < k0 + 256; kt += 16) {
#pragma unroll
    for (int q = 0; q < 4; q++) {
      int idx = tid + 256 * q;
      int kkx = idx & 15, rr = idx >> 4;
      As[kkx][rr] = A[(size_t)(rowBase + rr) * KK + kt + kkx];
      int kk = (tid >> 6) * 4 + q;
      int jj = tid & 63;
      Bs[kk][jj] = Bm[(size_t)(kt + kk) * DD + colBase + jj];
    }
    __syncthreads();
#pragma unroll
    for (int kx = 0; kx < 16; kx++) {
      float4 a4 = *(const float4*)&As[kx][ty * 4];
      float4 b4 = *(const float4*)&Bs[kx][tx * 4];
      float av[4] = {a4.x, a4.y, a4.z, a4.w};
      float bv[4] = {b4.x, b4.y, b4.z, b4.w};
#pragma unroll
      for (int r = 0; r < 4; r++)
#pragma unroll
        for (int q = 0; q < 4; q++)
          c[r][q] = fmaf(av[r], bv[q], c[r][q]);
    }
    __syncthreads();
  }
  float* dst = CPN + (size_t)blockIdx.z * BB * DD;
#pragma unroll
  for (int r = 0; r < 4; r++)
#pragma unroll
    for (int q = 0; q < 4; q++)
      dst[(size_t)(rowBase + ty * 4 + r) * DD + colBase + tx * 4 + q] = c[r][q];
}

// sum aggn split-K partials (S=2), emit sumsq partials; grid (4096, 2)
__global__ __launch_bounds__(256)
void k_reduce_n(const float* __restrict__ CPN, float* __restrict__ D0,
                float* __restrict__ D1, float* __restrict__ sqp) {
  __shared__ float sq[256];
  int tid = threadIdx.x, br = blockIdx.y;
  int i = blockIdx.x * 256 + tid;
  const int MN = BB * DD;
  float v = CPN[(size_t)(2 * br) * MN + i] + CPN[(size_t)(2 * br + 1) * MN + i];
  float* dst = br ? D1 : D0;
  dst[i] = v;
  sq[tid] = v * v; __syncthreads();
  for (int off = 128; off > 0; off >>= 1) {
    if (tid < off) sq[tid] += sq[tid + off];
    __syncthreads();
  }
  if (tid == 0) sqp[br * 4096 + blockIdx.x] = sq[0];
}

// agg_k partials = BIN @ feat (NN), split-K S=16; grid (DD/64, KK/64, 32); z = br*16+s
__global__ __launch_bounds__(256)
void k_gemm_aggk(const float* __restrict__ BIN, const float* __restrict__ B0,
                 const float* __restrict__ B1, float* __restrict__ CP) {
  __shared__ float As[16][68], Bs[16][68];
  int tid = threadIdx.x;
  int tx = tid & 15, ty = tid >> 4;
  int rowBase = blockIdx.y * 64, colBase = blockIdx.x * 64;
  int br = blockIdx.z >> 4, s = blockIdx.z & 15;
  const float* A = BIN + (size_t)br * KK * BB;
  const float* Bm = br ? B1 : B0;
  int k0 = s * 256;
  float c[4][4] = {};
  for (int kt = k0; kt < k0 + 256; kt += 16) {
#pragma unroll
    for (int q = 0; q < 4; q++) {
      int idx = tid + 256 * q;
      int kkx = idx & 15, rr = idx >> 4;
      As[kkx][rr] = A[(size_t)(rowBase + rr) * BB + kt + kkx];
      int kk = (tid >> 6) * 4 + q;
      int jj = tid & 63;
      Bs[kk][jj] = Bm[(size_t)(kt + kk) * DD + colBase + jj];
    }
    __syncthreads();
#pragma unroll
    for (int kx = 0; kx < 16; kx++) {
      float4 a4 = *(const float4*)&As[kx][ty * 4];
      float4 b4 = *(const float4*)&Bs[kx][tx * 4];
      float av[4] = {a4.x, a4.y, a4.z, a4.w};
      float bv[4] = {b4.x, b4.y, b4.z, b4.w};
#pragma unroll
      for (int r = 0; r < 4; r++)
#pragma unroll
        for (int q = 0; q < 4; q++)
          c[r][q] = fmaf(av[r], bv[q], c[r][q]);
    }
    __syncthreads();
  }
  float* dst = CP + (size_t)blockIdx.z * KK * DD;
#pragma unroll
  for (int r = 0; r < 4; r++)
#pragma unroll
    for (int q = 0; q < 4; q++)
      dst[(size_t)(rowBase + ty * 4 + r) * DD + colBase + tx * 4 + q] = c[r][q];
}

// sum aggk split-K partials (S=16), divide by row-sum, sumsq partials; grid (512, 2)
__global__ __launch_bounds__(256)
void k_reduce_div(const float* __restrict__ CP, const float* __restrict__ rs2,
                  float* __restrict__ D0, float* __restrict__ D1,
                  float* __restrict__ sqp) {
  __shared__ float sq[256];
  int tid = threadIdx.x, br = blockIdx.y;
  int i = blockIdx.x * 256 + tid;
  const int MN = KK * DD;
  const float* cp = CP + (size_t)br * 16 * MN;
  float s = 0.0f;
  for (int t = 0; t < 16; t++) s += cp[(size_t)t * MN + i];
  float v = s / (rs2[br * KK + (i >> 8)] + 1e-8f);
  float* dst = br ? D1 : D0;
  dst[i] = v;
  sq[tid] = v * v; __syncthreads();
  for (int off = 128; off > 0; off >>= 1) {
    if (tid < off) sq[tid] += sq[tid + off];
    __syncthreads();
  }
  if (tid == 0) sqp[br * 512 + blockIdx.x] = sq[0];
}

// reduce sumsq partials -> rsqrt; scale in place; grid (nblk, 2)
__global__ __launch_bounds__(256)
void k_scale_cvt(float* __restrict__ D0, float* __restrict__ D1,
                 const float* __restrict__ sqp, int np, int n) {
  __shared__ float sm[256];
  int tid = threadIdx.x, br = blockIdx.y;
  const float* sq = sqp + br * np;
  float a = 0.0f;
  for (int i = tid; i < np; i += 256) a += sq[i];
  sm[tid] = a; __syncthreads();
  for (int off = 128; off > 0; off >>= 1) {
    if (tid < off) sm[tid] += sm[tid + off];
    __syncthreads();
  }
  float f = (float)(1.0 / sqrt((double)fmaxf(sm[0], 1e-12f)));
  float* data = br ? D1 : D0;
  int i = (blockIdx.x * 256 + tid) * 4;
  if (i < n) {
    float4 v = *(const float4*)(data + i);
    v.x *= f; v.y *= f; v.z *= f; v.w *= f;
    *(float4*)(data + i) = v;
  }
}

// ---------------- softmax(y1) + hard argmax(y2), batched over branches ----------------
__global__ __launch_bounds__(256)
void k_softmax_assign(const float* __restrict__ T, float* __restrict__ Y,
                      float* __restrict__ assignOut,
                      u32 g1a0, u32 g1b0, u32 g1a1, u32 g1b1, u32 g2a, u32 g2b) {
  __shared__ float smA[4], smS[4], smM2[4], smS2[4], smV[4];
  __shared__ int smI[4];
  int bid = blockIdx.x, tid = threadIdx.x;
  int br = bid >> 12, b = bid & 4095;
  u32 g1a = br ? g1a1 : g1a0, g1b = br ? g1b1 : g1b0;
  const float* knT = T + (size_t)br * BB * KK;
  float* Yd = Y + (size_t)br * BB * KK;
  int lane = tid & 63, wid = tid >> 6;
  int i0 = b * KK + tid, i1 = i0 + 256;
  float x0 = knT[i0], x1 = knT[i1];

  float z0 = x0 + gumbel_f32(g1a, g1b, (u32)i0);
  float z1 = x1 + gumbel_f32(g1a, g1b, (u32)i1);
  float wm = fmaxf(z0, z1);
#pragma unroll
  for (int off = 1; off < 64; off <<= 1) wm = fmaxf(wm, __shfl_xor(wm, off, 64));
  if (lane == 0) smA[wid] = wm;
  __syncthreads();
  float m = fmaxf(fmaxf(smA[0], smA[1]), fmaxf(smA[2], smA[3]));
  float e0 = expf(z0 - m), e1 = expf(z1 - m);
  float ws = e0 + e1;
#pragma unroll
  for (int off = 1; off < 64; off <<= 1) ws += __shfl_xor(ws, off, 64);
  if (lane == 0) smS[wid] = ws;
  __syncthreads();
  float s = (smS[0] + smS[1]) + (smS[2] + smS[3]);
  Yd[i0] = e0 / s;
  Yd[i1] = e1 / s;

  if (br == 0) {
    float w0 = x0 + gumbel_at(g2a, g2b, (u32)i0);
    float w1 = x1 + gumbel_at(g2a, g2b, (u32)i1);
    float wm2 = fmaxf(w0, w1);
#pragma unroll
    for (int off = 1; off < 64; off <<= 1) wm2 = fmaxf(wm2, __shfl_xor(wm2, off, 64));
    if (lane == 0) smM2[wid] = wm2;
    __syncthreads();
    float m2 = fmaxf(fmaxf(smM2[0], smM2[1]), fmaxf(smM2[2], smM2[3]));
    float f0 = expf(w0 - m2), f1 = expf(w1 - m2);
    float ws2 = f0 + f1;
#pragma unroll
    for (int off = 1; off < 64; off <<= 1) ws2 += __shfl_xor(ws2, off, 64);
    if (lane == 0) smS2[wid] = ws2;
    __syncthreads();
    float s2 = (smS2[0] + smS2[1]) + (smS2[2] + smS2[3]);
    float y0 = f0 / s2, y1v = f1 / s2;
    float bv; int bi;
    if (y1v > y0) { bv = y1v; bi = tid + 256; } else { bv = y0; bi = tid; }
#pragma unroll
    for (int off = 1; off < 64; off <<= 1) {
      float ov = __shfl_xor(bv, off, 64);
      int oi = __shfl_xor(bi, off, 64);
      if (ov > bv || (ov == bv && oi < bi)) { bv = ov; bi = oi; }
    }
    if (lane == 0) { smV[wid] = bv; smI[wid] = bi; }
    __syncthreads();
    if (tid == 0) {
      float cv = smV[0]; int ci = smI[0];
#pragma unroll
      for (int t = 1; t < 4; t++) {
        if (smV[t] > cv || (smV[t] == cv && smI[t] < ci)) { cv = smV[t]; ci = smI[t]; }
      }
      assignOut[b] = (float)ci;
    }
  }
}

// ---------------- stochastic binary, 64b x 32k tiles, grid 2048 (8 blk/CU) ----------------
__global__ __launch_bounds__(256)
void k_binary(const float* __restrict__ T, float* __restrict__ BIN,
              float* __restrict__ rs2,
              u32 k3a0, u32 k3b0, u32 k3a1, u32 k3b1) {
  __shared__ float lds[64][33];
  int tid = threadIdx.x;
  int bid = blockIdx.x;
  int br = bid >> 10, t = bid & 1023;
  u32 k3a = br ? k3a1 : k3a0, k3b = br ? k3b1 : k3b0;
  const float* Tb = T + (size_t)br * BB * KK;
  float* Bd = BIN + (size_t)br * KK * BB;
  float* rs = rs2 + br * KK;
  int b0 = (t & 63) * 64;
  int k0 = (t >> 6) * 32;
  int cl32 = tid & 31, rl8 = tid >> 5;
  for (int bb = rl8; bb < 64; bb += 8)
    lds[bb][cl32] = Tb[(size_t)(b0 + bb) * KK + k0 + cl32];
  __syncthreads();
  int l = tid & 63, g = tid >> 6;
  for (int kk = g; kk < 32; kk += 4) {
    int k = k0 + kk, b = b0 + l;
    float x = lds[l][kk];
    float prob = 1.0f / (1.0f + expf(-x));
    u32 i = (u32)(k * BB + b);
    float eps = u01f(rbits32(k3a, k3b, i));
    float bin = (prob > eps) ? 1.0f : 0.0f;
    Bd[(size_t)k * BB + b] = bin;
    float srow = bin;
#pragma unroll
    for (int off = 1; off < 64; off <<= 1) srow += __shfl_xor(srow, off, 64);
    if (l == 0) atomicAdd(rs + k, srow);
  }
}

// ---------------- Taylor-collapsed InfoNCE loss, batched (1152 blocks) ----------------
__global__ __launch_bounds__(256)
void k_loss_row(const float* __restrict__ QN, const float* __restrict__ KPN,
                const float* __restrict__ QK, const float* __restrict__ KPK,
                const float* __restrict__ csum, const float* __restrict__ lscp,
                float* __restrict__ LPN, float* __restrict__ LPK) {
  __shared__ float pt[4];
  int w = threadIdx.x >> 6, l = threadIdx.x & 63;
  int bid = blockIdx.x;
  int isK = (bid >= 1024);
  int rb = isK ? (bid - 1024) : bid;
  const float* Q  = isK ? QK : QN;
  const float* KP = isK ? KPK : KPN;
  const float* cs4 = csum + (isK ? 256 : 0);
  float Lc = isK ? (float)QQ : (float)LL;
  float lsc = lscp[isK ? 1 : 0];
  int r = rb * 4 + w;
  float4 q = *(const float4*)(Q + (size_t)r * 256 + l * 4);
  float4 kp = *(const float4*)(KP + (size_t)r * 256 + l * 4);
  float4 cs = *(const float4*)(cs4 + l * 4);
  float d1 = q.x * kp.x + q.y * kp.y + q.z * kp.z + q.w * kp.w;
  float d2 = q.x * cs.x + q.y * cs.y + q.z * cs.z + q.w * cs.w;
#pragma unroll
  for (int off = 1; off < 64; off <<= 1) {
    d1 += __shfl_xor(d1, off, 64);
    d2 += __shfl_xor(d2, off, 64);
  }
  if (l == 0) {
    float z0 = d1 / 0.07f;
    double S = (double)Lc + (double)expf(z0) + (double)(lsc * d2);
    pt[w] = (float)(log(S)) - z0;
  }
  __syncthreads();
  if (threadIdx.x == 0) {
    float v = (pt[0] + pt[1]) + (pt[2] + pt[3]);
    if (isK) LPK[rb] = v; else LPN[rb] = v;
  }
}

__global__ __launch_bounds__(256)
void k_loss_final(const float* __restrict__ LPN, int nN, float invMN,
                  const float* __restrict__ LPK, int nK, float invMK,
                  float* __restrict__ outLoss) {
  __shared__ float sm[256];
  int tid = threadIdx.x;
  float a = 0.0f;
  for (int i = tid; i < nN; i += 256) a += LPN[i];
  sm[tid] = a; __syncthreads();
  for (int off = 128; off > 0; off >>= 1) {
    if (tid < off) sm[tid] += sm[tid + off];
    __syncthreads();
  }
  float lossN = sm[0] * invMN;
  __syncthreads();
  float b = 0.0f;
  for (int i = tid; i < nK; i += 256) b += LPK[i];
  sm[tid] = b; __syncthreads();
  for (int off = 128; off > 0; off >>= 1) {
    if (tid < off) sm[tid] += sm[tid + off];
    __syncthreads();
  }
  if (tid == 0) outLoss[0] = lossN + sm[0] * invMK;
}

// ---------------- launch ----------------
extern "C" void kernel_launch(void* const* d_in, const int* in_sizes, int n_in,
                              void* d_out, int out_size, void* d_ws, size_t ws_size,
                              hipStream_t stream) {
  const float* feat0 = (const float*)d_in[0];
  const float* feat1 = (const float*)d_in[1];
  const float* ctx0  = (const float*)d_in[2];
  const float* ctx1  = (const float*)d_in[3];
  const float* queue_n = (const float*)d_in[4];
  const float* queue_k = (const float*)d_in[5];

  float* W = (float*)d_ws;
  size_t o = 0;
  float* T     = W + o; o += 2 * (size_t)BB * KK;
  float* Yb    = W + o; o += 2 * (size_t)BB * KK;
  float* BIN   = W + o; o += 2 * (size_t)KK * BB;
  float* CP    = W + o; o += 32 * (size_t)KK * DD;   // aggk partials [2*16][K][D]
  float* CPN   = W + o; o += 4 * (size_t)BB * DD;    // aggn partials [2*2][B][D]
  float* AGGN1 = W + o; o += (size_t)BB * DD;
  float* AGGK1 = W + o; o += (size_t)KK * DD;
  float* RS2   = W + o; o += 2 * KK;
  float* CPS   = W + o; o += 2 * 131072;
  float* SQ2   = W + o; o += 2 * 512;
  float* CS    = W + o; o += 2 * 256;
  float* LSC   = W + o; o += 2;
  float* LPN   = W + o; o += 1024;
  float* LPK   = W + o; o += 128;
  float* PART_K = W + o; o += 256;
  float* SQPN  = W + o; o += 2 * 4096;
  float* SQPK  = W + o; o += 2 * 512;

  float* out = (float*)d_out;
  float* outAssign = out;
  float* outAggn2  = out + BB;
  float* outAggk2  = out + BB + (size_t)BB * DD;
  float* outLoss   = out + BB + (size_t)BB * DD + (size_t)KK * DD;

  u32 kq0, kq1, kc[2][2];
  tf2x32(0u, 42u, 0u, 0u, kq0, kq1);
  tf2x32(0u, 42u, 0u, 1u, kc[0][0], kc[0][1]);
  tf2x32(0u, 42u, 0u, 2u, kc[1][0], kc[1][1]);
  u32 sub[2][3][2];
  for (int br = 0; br < 2; br++)
    for (int t = 0; t < 3; t++)
      tf2x32(kc[br][0], kc[br][1], 0u, (u32)t, sub[br][t][0], sub[br][t][1]);

  // stats chain
  k_sumsq<<<256, 256, 0, stream>>>(queue_k, QQ * DD, PART_K);
  k_stats<<<dim3(512, 2), 256, 0, stream>>>(queue_n, queue_k, PART_K, CPS, SQ2, kq0, kq1);
  k_finalize_csum<<<dim3(256, 2), 256, 0, stream>>>(CPS, CS);
  k_finalize_lsc<<<2, 256, 0, stream>>>(SQ2, LSC);

  hipMemsetAsync(RS2, 0, 2 * KK * sizeof(float), stream);

  // batched branch pipeline (all GEMMs >= 4 blocks/CU)
  k_gemm_nt<<<dim3(KK / 64, BB / 64, 2), 256, 0, stream>>>(feat0, feat1, ctx0, ctx1, T, KK);
  k_softmax_assign<<<2 * BB, 256, 0, stream>>>(T, Yb, outAssign,
      sub[0][0][0], sub[0][0][1], sub[1][0][0], sub[1][0][1], sub[0][1][0], sub[0][1][1]);
  k_binary<<<2048, 256, 0, stream>>>(T, BIN, RS2,
      sub[0][2][0], sub[0][2][1], sub[1][2][0], sub[1][2][1]);
  k_gemm_aggn<<<dim3(DD / 64, BB / 64, 4), 256, 0, stream>>>(Yb, ctx0, ctx1, CPN);
  k_reduce_n<<<dim3(BB * DD / 256, 2), 256, 0, stream>>>(CPN, AGGN1, outAggn2, SQPN);
  k_gemm_aggk<<<dim3(DD / 64, KK / 64, 32), 256, 0, stream>>>(BIN, feat0, feat1, CP);
  k_reduce_div<<<dim3(KK * DD / 256, 2), 256, 0, stream>>>(CP, RS2, AGGK1, outAggk2, SQPK);
  k_scale_cvt<<<dim3(BB * DD / 1024, 2), 256, 0, stream>>>(AGGN1, outAggn2, SQPN, 4096, BB * DD);
  k_scale_cvt<<<dim3(KK * DD / 1024, 2), 256, 0, stream>>>(AGGK1, outAggk2, SQPK, 512, KK * DD);

  // Taylor-collapsed losses
  k_loss_row<<<1152, 256, 0, stream>>>(AGGN1, outAggn2, AGGK1, outAggk2, CS, LSC, LPN, LPK);
  k_loss_final<<<1, 256, 0, stream>>>(LPN, BB / 4, 1.0f / BB, LPK, KK / 4, 1.0f / KK, outLoss);
}

// Round 16
// 228.220 us; speedup vs baseline: 1.2658x; 1.0977x over previous
//
#include <hip/hip_runtime.h>
#include <stdint.h>
#include <math.h>

typedef unsigned int u32;

#define BB 4096
#define DD 256
#define KK 512
#define LL 32768
#define QQ 8192

// ---------------- Threefry2x32 (JAX-exact, 20 rounds) ----------------
__host__ __device__ inline void tf2x32(u32 k0, u32 k1, u32 c0, u32 c1, u32& o0, u32& o1) {
  u32 ks2 = k0 ^ k1 ^ 0x1BD11BDAu;
  u32 x0 = c0 + k0, x1 = c1 + k1;
#define TF_R(r) { x0 += x1; x1 = ((x1 << (r)) | (x1 >> (32 - (r)))); x1 ^= x0; }
  TF_R(13) TF_R(15) TF_R(26) TF_R(6)
  x0 += k1; x1 += ks2 + 1u;
  TF_R(17) TF_R(29) TF_R(16) TF_R(24)
  x0 += ks2; x1 += k0 + 2u;
  TF_R(13) TF_R(15) TF_R(26) TF_R(6)
  x0 += k0; x1 += k1 + 3u;
  TF_R(17) TF_R(29) TF_R(16) TF_R(24)
  x0 += k1; x1 += ks2 + 4u;
  TF_R(13) TF_R(15) TF_R(26) TF_R(6)
  x0 += ks2; x1 += k0 + 5u;
#undef TF_R
  o0 = x0; o1 = x1;
}

__device__ inline u32 rbits32(u32 k0, u32 k1, u32 i) {
  u32 a, b;
  tf2x32(k0, k1, 0u, i, a, b);
  return a ^ b;
}

__device__ inline float u01f(u32 bits) {
  return __uint_as_float(0x3f800000u | (bits >> 9)) - 1.0f;
}

// f64-log gumbel: argmax-critical path only (bit-stable vs CPU libm)
__device__ inline float gumbel_at(u32 k0, u32 k1, u32 i) {
  float f = u01f(rbits32(k0, k1, i));
  float u = fmaxf(1e-20f, f + 1e-20f);
  float l1 = (float)log((double)u);
  float l2 = (float)log((double)(-l1));
  return -l2;
}

// fast f32 gumbel: continuous-output paths (y1 softmax)
__device__ inline float gumbel_f32(u32 k0, u32 k1, u32 i) {
  float f = u01f(rbits32(k0, k1, i));
  float u = fmaxf(1e-20f, f + 1e-20f);
  float l1 = __logf(u);
  return -__logf(-l1);
}

// XLA f32 ErfInv (Giles polynomial)
__device__ inline float erfinv32(float x) {
  float w = -log1pf(-x * x);
  float p;
  if (w < 5.0f) {
    w -= 2.5f;
    p = 2.81022636e-08f;
    p = fmaf(p, w, 3.43273939e-07f);
    p = fmaf(p, w, -3.5233877e-06f);
    p = fmaf(p, w, -4.39150654e-06f);
    p = fmaf(p, w, 0.00021858087f);
    p = fmaf(p, w, -0.00125372503f);
    p = fmaf(p, w, -0.00417768164f);
    p = fmaf(p, w, 0.246640727f);
    p = fmaf(p, w, 1.50140941f);
  } else {
    w = sqrtf(w) - 3.0f;
    p = -0.000200214257f;
    p = fmaf(p, w, 0.000100950558f);
    p = fmaf(p, w, 0.00134934322f);
    p = fmaf(p, w, -0.00367342844f);
    p = fmaf(p, w, 0.00573950773f);
    p = fmaf(p, w, -0.0076224613f);
    p = fmaf(p, w, 0.00943887047f);
    p = fmaf(p, w, 1.00167406f);
    p = fmaf(p, w, 2.83297682f);
  }
  return p * x;
}

// ---------------- queue_k raw sumsq (for sk) ----------------
__global__ __launch_bounds__(256)
void k_sumsq(const float* __restrict__ x, int n, float* __restrict__ partial) {
  __shared__ float sm[256];
  float s = 0.0f;
  for (int i = blockIdx.x * 256 + threadIdx.x; i < n; i += gridDim.x * 256) {
    float v = x[i]; s = fmaf(v, v, s);
  }
  sm[threadIdx.x] = s; __syncthreads();
  for (int off = 128; off > 0; off >>= 1) {
    if (threadIdx.x < off) sm[threadIdx.x] += sm[threadIdx.x + off];
    __syncthreads();
  }
  if (threadIdx.x == 0) partial[blockIdx.x] = sm[0];
}

// ---------------- fused stats: z=0 queue_n (64 rows/blk), z=1 constructed queue (16 rows/blk)
__global__ __launch_bounds__(256)
void k_stats(const float* __restrict__ qn, const float* __restrict__ qk_in,
             const float* __restrict__ partK,
             float* __restrict__ colpart, float* __restrict__ sqpart,
             u32 kqa, u32 kqb) {
  __shared__ float smc[4][256];
  __shared__ float sm[256];
  int tid = threadIdx.x, g = tid >> 6, l = tid & 63;
  int z = blockIdx.y;
  float4 ca = {0.f, 0.f, 0.f, 0.f};
  float ss = 0.0f;
  if (z == 0) {
    int base = blockIdx.x * 64;
    for (int j = base + g; j < base + 64; j += 4) {
      float4 v = *(const float4*)(qn + (size_t)j * 256 + l * 4);
      ca.x += v.x; ca.y += v.y; ca.z += v.z; ca.w += v.w;
      ss = fmaf(v.x, v.x, ss); ss = fmaf(v.y, v.y, ss);
      ss = fmaf(v.z, v.z, ss); ss = fmaf(v.w, v.w, ss);
    }
  } else {
    sm[tid] = partK[tid]; __syncthreads();
    for (int off = 128; off > 0; off >>= 1) {
      if (tid < off) sm[tid] += sm[tid + off];
      __syncthreads();
    }
    float sk = (float)(1.0 / sqrt((double)fmaxf(sm[0], 1e-12f)));
    __syncthreads();
    const float lo = -0.99999994f;
    int base = blockIdx.x * 16;
    for (int j = base + g; j < base + 16; j += 4) {
      int i0 = j * 256 + l * 4;
      float4 v = *(const float4*)(qk_in + i0);
      float vin[4] = {v.x, v.y, v.z, v.w};
      float valv[4];
#pragma unroll
      for (int e = 0; e < 4; e++) {
        float qk = vin[e] * sk;
        float f = u01f(rbits32(kqa, kqb, (u32)(i0 + e)));
        float u = fmaxf(lo, f * 2.0f + lo);
        float nv = 1.41421354f * erfinv32(u);
        float t = qk + 0.1f * nv;
        valv[e] = t + qk;
        ss = fmaf(valv[e], valv[e], ss);
      }
      ca.x += valv[0]; ca.y += valv[1]; ca.z += valv[2]; ca.w += valv[3];
    }
  }
  smc[g][l * 4 + 0] = ca.x; smc[g][l * 4 + 1] = ca.y;
  smc[g][l * 4 + 2] = ca.z; smc[g][l * 4 + 3] = ca.w;
  sm[tid] = ss; __syncthreads();
  colpart[(size_t)z * 131072 + blockIdx.x * 256 + tid] =
      (smc[0][tid] + smc[1][tid]) + (smc[2][tid] + smc[3][tid]);
  for (int off = 128; off > 0; off >>= 1) {
    if (tid < off) sm[tid] += sm[tid + off];
    __syncthreads();
  }
  if (tid == 0) sqpart[z * 512 + blockIdx.x] = sm[0];
}

// parallel finalize csum: grid (256, 2)
__global__ __launch_bounds__(256)
void k_finalize_csum(const float* __restrict__ colpart, float* __restrict__ csum) {
  __shared__ float sm[256];
  int d = blockIdx.x, z = blockIdx.y, t = threadIdx.x;
  const float* cp = colpart + (size_t)z * 131072;
  float a = cp[(size_t)t * 256 + d] + cp[(size_t)(t + 256) * 256 + d];
  sm[t] = a; __syncthreads();
  for (int off = 128; off > 0; off >>= 1) {
    if (t < off) sm[t] += sm[t + off];
    __syncthreads();
  }
  if (t == 0) csum[z * 256 + d] = sm[0];
}

// grid 2: lsc[z] = rsqrt(sum(sqpart[z]))/0.07
__global__ __launch_bounds__(256)
void k_finalize_lsc(const float* __restrict__ sqpart, float* __restrict__ lscOut) {
  __shared__ float sm[256];
  int t = threadIdx.x, z = blockIdx.x;
  const float* sq = sqpart + z * 512;
  float a = sq[t] + sq[t + 256];
  sm[t] = a; __syncthreads();
  for (int off = 128; off > 0; off >>= 1) {
    if (t < off) sm[t] += sm[t + off];
    __syncthreads();
  }
  if (t == 0) {
    float sr = (float)(1.0 / sqrt((double)fmaxf(sm[0], 1e-12f)));
    lscOut[z] = sr / 0.07f;
  }
}

// ---------------- f32 GEMMs: 64x64 tile, 4x4 register tile (proven shape) ----------------
__global__ __launch_bounds__(256)
void k_gemm_nt(const float* __restrict__ A0, const float* __restrict__ A1,
               const float* __restrict__ B0, const float* __restrict__ B1,
               float* __restrict__ C, int N) {
  __shared__ float As[16][68], Bs[16][68];
  int tid = threadIdx.x;
  int tx = tid & 15, ty = tid >> 4;
  int rowBase = blockIdx.y * 64, colBase = blockIdx.x * 64;
  int br = blockIdx.z;
  const float* A = br ? A1 : A0;
  const float* Bm = br ? B1 : B0;
  float* Cd = C + (size_t)br * BB * KK;
  float c[4][4] = {};
  for (int kt = 0; kt < 256; kt += 16) {
#pragma unroll
    for (int q = 0; q < 4; q++) {
      int idx = tid + 256 * q;
      int kkx = idx & 15, rr = idx >> 4;
      As[kkx][rr] = A[(size_t)(rowBase + rr) * 256 + kt + kkx];
      Bs[kkx][rr] = Bm[(size_t)(colBase + rr) * 256 + kt + kkx];
    }
    __syncthreads();
#pragma unroll
    for (int kx = 0; kx < 16; kx++) {
      float4 a4 = *(const float4*)&As[kx][ty * 4];
      float4 b4 = *(const float4*)&Bs[kx][tx * 4];
      float av[4] = {a4.x, a4.y, a4.z, a4.w};
      float bv[4] = {b4.x, b4.y, b4.z, b4.w};
#pragma unroll
      for (int r = 0; r < 4; r++)
#pragma unroll
        for (int q = 0; q < 4; q++)
          c[r][q] = fmaf(av[r], bv[q], c[r][q]);
    }
    __syncthreads();
  }
#pragma unroll
  for (int r = 0; r < 4; r++)
#pragma unroll
    for (int q = 0; q < 4; q++)
      Cd[(size_t)(rowBase + ty * 4 + r) * N + colBase + tx * 4 + q] = c[r][q];
}

// agg_n partials = Y @ ctx (NN), split-K S=2; grid (DD/64, BB/64, 4); z = br*2+s
__global__ __launch_bounds__(256)
void k_gemm_aggn(const float* __restrict__ Yb, const float* __restrict__ B0,
                 const float* __restrict__ B1, float* __restrict__ CPN) {
  __shared__ float As[16][68], Bs[16][68];
  int tid = threadIdx.x;
  int tx = tid & 15, ty = tid >> 4;
  int rowBase = blockIdx.y * 64, colBase = blockIdx.x * 64;
  int br = blockIdx.z >> 1, s = blockIdx.z & 1;
  const float* A = Yb + (size_t)br * BB * KK;
  const float* Bm = br ? B1 : B0;
  int k0 = s * 256;
  float c[4][4] = {};
  for (int kt = k0; kt < k0 + 256; kt += 16) {
#pragma unroll
    for (int q = 0; q < 4; q++) {
      int idx = tid + 256 * q;
      int kkx = idx & 15, rr = idx >> 4;
      As[kkx][rr] = A[(size_t)(rowBase + rr) * KK + kt + kkx];
      int kk = (tid >> 6) * 4 + q;
      int jj = tid & 63;
      Bs[kk][jj] = Bm[(size_t)(kt + kk) * DD + colBase + jj];
    }
    __syncthreads();
#pragma unroll
    for (int kx = 0; kx < 16; kx++) {
      float4 a4 = *(const float4*)&As[kx][ty * 4];
      float4 b4 = *(const float4*)&Bs[kx][tx * 4];
      float av[4] = {a4.x, a4.y, a4.z, a4.w};
      float bv[4] = {b4.x, b4.y, b4.z, b4.w};
#pragma unroll
      for (int r = 0; r < 4; r++)
#pragma unroll
        for (int q = 0; q < 4; q++)
          c[r][q] = fmaf(av[r], bv[q], c[r][q]);
    }
    __syncthreads();
  }
  float* dst = CPN + (size_t)blockIdx.z * BB * DD;
#pragma unroll
  for (int r = 0; r < 4; r++)
#pragma unroll
    for (int q = 0; q < 4; q++)
      dst[(size_t)(rowBase + ty * 4 + r) * DD + colBase + tx * 4 + q] = c[r][q];
}

// sum aggn split-K partials (S=2), emit sumsq partials; grid (4096, 2)
__global__ __launch_bounds__(256)
void k_reduce_n(const float* __restrict__ CPN, float* __restrict__ D0,
                float* __restrict__ D1, float* __restrict__ sqp) {
  __shared__ float sq[256];
  int tid = threadIdx.x, br = blockIdx.y;
  int i = blockIdx.x * 256 + tid;
  const int MN = BB * DD;
  float v = CPN[(size_t)(2 * br) * MN + i] + CPN[(size_t)(2 * br + 1) * MN + i];
  float* dst = br ? D1 : D0;
  dst[i] = v;
  sq[tid] = v * v; __syncthreads();
  for (int off = 128; off > 0; off >>= 1) {
    if (tid < off) sq[tid] += sq[tid + off];
    __syncthreads();
  }
  if (tid == 0) sqp[br * 4096 + blockIdx.x] = sq[0];
}

// agg_k partials = BIN @ feat (NN), split-K S=16; grid (DD/64, KK/64, 32); z = br*16+s
__global__ __launch_bounds__(256)
void k_gemm_aggk(const float* __restrict__ BIN, const float* __restrict__ B0,
                 const float* __restrict__ B1, float* __restrict__ CP) {
  __shared__ float As[16][68], Bs[16][68];
  int tid = threadIdx.x;
  int tx = tid & 15, ty = tid >> 4;
  int rowBase = blockIdx.y * 64, colBase = blockIdx.x * 64;
  int br = blockIdx.z >> 4, s = blockIdx.z & 15;
  const float* A = BIN + (size_t)br * KK * BB;
  const float* Bm = br ? B1 : B0;
  int k0 = s * 256;
  float c[4][4] = {};
  for (int kt = k0; kt < k0 + 256; kt += 16) {
#pragma unroll
    for (int q = 0; q < 4; q++) {
      int idx = tid + 256 * q;
      int kkx = idx & 15, rr = idx >> 4;
      As[kkx][rr] = A[(size_t)(rowBase + rr) * BB + kt + kkx];
      int kk = (tid >> 6) * 4 + q;
      int jj = tid & 63;
      Bs[kk][jj] = Bm[(size_t)(kt + kk) * DD + colBase + jj];
    }
    __syncthreads();
#pragma unroll
    for (int kx = 0; kx < 16; kx++) {
      float4 a4 = *(const float4*)&As[kx][ty * 4];
      float4 b4 = *(const float4*)&Bs[kx][tx * 4];
      float av[4] = {a4.x, a4.y, a4.z, a4.w};
      float bv[4] = {b4.x, b4.y, b4.z, b4.w};
#pragma unroll
      for (int r = 0; r < 4; r++)
#pragma unroll
        for (int q = 0; q < 4; q++)
          c[r][q] = fmaf(av[r], bv[q], c[r][q]);
    }
    __syncthreads();
  }
  float* dst = CP + (size_t)blockIdx.z * KK * DD;
#pragma unroll
  for (int r = 0; r < 4; r++)
#pragma unroll
    for (int q = 0; q < 4; q++)
      dst[(size_t)(rowBase + ty * 4 + r) * DD + colBase + tx * 4 + q] = c[r][q];
}

// sum aggk split-K partials (S=16), divide by row-sum, sumsq partials; grid (512, 2)
__global__ __launch_bounds__(256)
void k_reduce_div(const float* __restrict__ CP, const float* __restrict__ rs2,
                  float* __restrict__ D0, float* __restrict__ D1,
                  float* __restrict__ sqp) {
  __shared__ float sq[256];
  int tid = threadIdx.x, br = blockIdx.y;
  int i = blockIdx.x * 256 + tid;
  const int MN = KK * DD;
  const float* cp = CP + (size_t)br * 16 * MN;
  float s = 0.0f;
  for (int t = 0; t < 16; t++) s += cp[(size_t)t * MN + i];
  float v = s / (rs2[br * KK + (i >> 8)] + 1e-8f);
  float* dst = br ? D1 : D0;
  dst[i] = v;
  sq[tid] = v * v; __syncthreads();
  for (int off = 128; off > 0; off >>= 1) {
    if (tid < off) sq[tid] += sq[tid + off];
    __syncthreads();
  }
  if (tid == 0) sqp[br * 512 + blockIdx.x] = sq[0];
}

// reduce sumsq partials -> rsqrt; scale in place; grid (nblk, 2)
__global__ __launch_bounds__(256)
void k_scale_cvt(float* __restrict__ D0, float* __restrict__ D1,
                 const float* __restrict__ sqp, int np, int n) {
  __shared__ float sm[256];
  int tid = threadIdx.x, br = blockIdx.y;
  const float* sq = sqp + br * np;
  float a = 0.0f;
  for (int i = tid; i < np; i += 256) a += sq[i];
  sm[tid] = a; __syncthreads();
  for (int off = 128; off > 0; off >>= 1) {
    if (tid < off) sm[tid] += sm[tid + off];
    __syncthreads();
  }
  float f = (float)(1.0 / sqrt((double)fmaxf(sm[0], 1e-12f)));
  float* data = br ? D1 : D0;
  int i = (blockIdx.x * 256 + tid) * 4;
  if (i < n) {
    float4 v = *(const float4*)(data + i);
    v.x *= f; v.y *= f; v.z *= f; v.w *= f;
    *(float4*)(data + i) = v;
  }
}

// ---------------- softmax(y1) + hard argmax(y2), batched over branches ----------------
__global__ __launch_bounds__(256)
void k_softmax_assign(const float* __restrict__ T, float* __restrict__ Y,
                      float* __restrict__ assignOut,
                      u32 g1a0, u32 g1b0, u32 g1a1, u32 g1b1, u32 g2a, u32 g2b) {
  __shared__ float smA[4], smS[4], smM2[4], smS2[4], smV[4];
  __shared__ int smI[4];
  int bid = blockIdx.x, tid = threadIdx.x;
  int br = bid >> 12, b = bid & 4095;
  u32 g1a = br ? g1a1 : g1a0, g1b = br ? g1b1 : g1b0;
  const float* knT = T + (size_t)br * BB * KK;
  float* Yd = Y + (size_t)br * BB * KK;
  int lane = tid & 63, wid = tid >> 6;
  int i0 = b * KK + tid, i1 = i0 + 256;
  float x0 = knT[i0], x1 = knT[i1];

  float z0 = x0 + gumbel_f32(g1a, g1b, (u32)i0);
  float z1 = x1 + gumbel_f32(g1a, g1b, (u32)i1);
  float wm = fmaxf(z0, z1);
#pragma unroll
  for (int off = 1; off < 64; off <<= 1) wm = fmaxf(wm, __shfl_xor(wm, off, 64));
  if (lane == 0) smA[wid] = wm;
  __syncthreads();
  float m = fmaxf(fmaxf(smA[0], smA[1]), fmaxf(smA[2], smA[3]));
  float e0 = expf(z0 - m), e1 = expf(z1 - m);
  float ws = e0 + e1;
#pragma unroll
  for (int off = 1; off < 64; off <<= 1) ws += __shfl_xor(ws, off, 64);
  if (lane == 0) smS[wid] = ws;
  __syncthreads();
  float s = (smS[0] + smS[1]) + (smS[2] + smS[3]);
  Yd[i0] = e0 / s;
  Yd[i1] = e1 / s;

  if (br == 0) {
    float w0 = x0 + gumbel_at(g2a, g2b, (u32)i0);
    float w1 = x1 + gumbel_at(g2a, g2b, (u32)i1);
    float wm2 = fmaxf(w0, w1);
#pragma unroll
    for (int off = 1; off < 64; off <<= 1) wm2 = fmaxf(wm2, __shfl_xor(wm2, off, 64));
    if (lane == 0) smM2[wid] = wm2;
    __syncthreads();
    float m2 = fmaxf(fmaxf(smM2[0], smM2[1]), fmaxf(smM2[2], smM2[3]));
    float f0 = expf(w0 - m2), f1 = expf(w1 - m2);
    float ws2 = f0 + f1;
#pragma unroll
    for (int off = 1; off < 64; off <<= 1) ws2 += __shfl_xor(ws2, off, 64);
    if (lane == 0) smS2[wid] = ws2;
    __syncthreads();
    float s2 = (smS2[0] + smS2[1]) + (smS2[2] + smS2[3]);
    float y0 = f0 / s2, y1v = f1 / s2;
    float bv; int bi;
    if (y1v > y0) { bv = y1v; bi = tid + 256; } else { bv = y0; bi = tid; }
#pragma unroll
    for (int off = 1; off < 64; off <<= 1) {
      float ov = __shfl_xor(bv, off, 64);
      int oi = __shfl_xor(bi, off, 64);
      if (ov > bv || (ov == bv && oi < bi)) { bv = ov; bi = oi; }
    }
    if (lane == 0) { smV[wid] = bv; smI[wid] = bi; }
    __syncthreads();
    if (tid == 0) {
      float cv = smV[0]; int ci = smI[0];
#pragma unroll
      for (int t = 1; t < 4; t++) {
        if (smV[t] > cv || (smV[t] == cv && smI[t] < ci)) { cv = smV[t]; ci = smI[t]; }
      }
      assignOut[b] = (float)ci;
    }
  }
}

// ---------------- stochastic binary, write-only (rowsum moved out) ----------------
// 64b x 32k tiles, grid 2048 (8 blk/CU). No reduce/atomics: pure
// load->threefry->compare->store. RNG indices/compares bit-identical.
__global__ __launch_bounds__(256)
void k_binary(const float* __restrict__ T, float* __restrict__ BIN,
              u32 k3a0, u32 k3b0, u32 k3a1, u32 k3b1) {
  __shared__ float lds[64][33];
  int tid = threadIdx.x;
  int bid = blockIdx.x;
  int br = bid >> 10, t = bid & 1023;
  u32 k3a = br ? k3a1 : k3a0, k3b = br ? k3b1 : k3b0;
  const float* Tb = T + (size_t)br * BB * KK;
  float* Bd = BIN + (size_t)br * KK * BB;
  int b0 = (t & 63) * 64;
  int k0 = (t >> 6) * 32;
  int cl32 = tid & 31, rl8 = tid >> 5;
  for (int bb = rl8; bb < 64; bb += 8)
    lds[bb][cl32] = Tb[(size_t)(b0 + bb) * KK + k0 + cl32];
  __syncthreads();
  int l = tid & 63, g = tid >> 6;
  for (int kk = g; kk < 32; kk += 4) {
    int k = k0 + kk, b = b0 + l;
    float x = lds[l][kk];
    float prob = 1.0f / (1.0f + expf(-x));
    u32 i = (u32)(k * BB + b);
    float eps = u01f(rbits32(k3a, k3b, i));
    Bd[(size_t)k * BB + b] = (prob > eps) ? 1.0f : 0.0f;
  }
}

// ---------------- row sums of BIN: one block per (br,k) row, coalesced ----------------
// Whole-number sums (< 2^13) are exact in fp32 regardless of order.
__global__ __launch_bounds__(256)
void k_rowsum(const float* __restrict__ BIN, float* __restrict__ rs2) {
  __shared__ float sm[4];
  int row = blockIdx.x;                  // 0..1023 over [2][KK]
  const float* src = BIN + (size_t)row * BB;
  int tid = threadIdx.x, l = tid & 63, w = tid >> 6;
  float s = 0.0f;
#pragma unroll
  for (int p = 0; p < 4; p++) {
    float4 v = *(const float4*)(src + (p * 256 + tid) * 4);
    s += (v.x + v.y) + (v.z + v.w);
  }
#pragma unroll
  for (int off = 1; off < 64; off <<= 1) s += __shfl_xor(s, off, 64);
  if (l == 0) sm[w] = s;
  __syncthreads();
  if (tid == 0) rs2[row] = (sm[0] + sm[1]) + (sm[2] + sm[3]);
}

// ---------------- Taylor-collapsed InfoNCE loss, batched (1152 blocks) ----------------
__global__ __launch_bounds__(256)
void k_loss_row(const float* __restrict__ QN, const float* __restrict__ KPN,
                const float* __restrict__ QK, const float* __restrict__ KPK,
                const float* __restrict__ csum, const float* __restrict__ lscp,
                float* __restrict__ LPN, float* __restrict__ LPK) {
  __shared__ float pt[4];
  int w = threadIdx.x >> 6, l = threadIdx.x & 63;
  int bid = blockIdx.x;
  int isK = (bid >= 1024);
  int rb = isK ? (bid - 1024) : bid;
  const float* Q  = isK ? QK : QN;
  const float* KP = isK ? KPK : KPN;
  const float* cs4 = csum + (isK ? 256 : 0);
  float Lc = isK ? (float)QQ : (float)LL;
  float lsc = lscp[isK ? 1 : 0];
  int r = rb * 4 + w;
  float4 q = *(const float4*)(Q + (size_t)r * 256 + l * 4);
  float4 kp = *(const float4*)(KP + (size_t)r * 256 + l * 4);
  float4 cs = *(const float4*)(cs4 + l * 4);
  float d1 = q.x * kp.x + q.y * kp.y + q.z * kp.z + q.w * kp.w;
  float d2 = q.x * cs.x + q.y * cs.y + q.z * cs.z + q.w * cs.w;
#pragma unroll
  for (int off = 1; off < 64; off <<= 1) {
    d1 += __shfl_xor(d1, off, 64);
    d2 += __shfl_xor(d2, off, 64);
  }
  if (l == 0) {
    float z0 = d1 / 0.07f;
    double S = (double)Lc + (double)expf(z0) + (double)(lsc * d2);
    pt[w] = (float)(log(S)) - z0;
  }
  __syncthreads();
  if (threadIdx.x == 0) {
    float v = (pt[0] + pt[1]) + (pt[2] + pt[3]);
    if (isK) LPK[rb] = v; else LPN[rb] = v;
  }
}

__global__ __launch_bounds__(256)
void k_loss_final(const float* __restrict__ LPN, int nN, float invMN,
                  const float* __restrict__ LPK, int nK, float invMK,
                  float* __restrict__ outLoss) {
  __shared__ float sm[256];
  int tid = threadIdx.x;
  float a = 0.0f;
  for (int i = tid; i < nN; i += 256) a += LPN[i];
  sm[tid] = a; __syncthreads();
  for (int off = 128; off > 0; off >>= 1) {
    if (tid < off) sm[tid] += sm[tid + off];
    __syncthreads();
  }
  float lossN = sm[0] * invMN;
  __syncthreads();
  float b = 0.0f;
  for (int i = tid; i < nK; i += 256) b += LPK[i];
  sm[tid] = b; __syncthreads();
  for (int off = 128; off > 0; off >>= 1) {
    if (tid < off) sm[tid] += sm[tid + off];
    __syncthreads();
  }
  if (tid == 0) outLoss[0] = lossN + sm[0] * invMK;
}

// ---------------- launch ----------------
extern "C" void kernel_launch(void* const* d_in, const int* in_sizes, int n_in,
                              void* d_out, int out_size, void* d_ws, size_t ws_size,
                              hipStream_t stream) {
  const float* feat0 = (const float*)d_in[0];
  const float* feat1 = (const float*)d_in[1];
  const float* ctx0  = (const float*)d_in[2];
  const float* ctx1  = (const float*)d_in[3];
  const float* queue_n = (const float*)d_in[4];
  const float* queue_k = (const float*)d_in[5];

  float* W = (float*)d_ws;
  size_t o = 0;
  float* T     = W + o; o += 2 * (size_t)BB * KK;
  float* Yb    = W + o; o += 2 * (size_t)BB * KK;
  float* BIN   = W + o; o += 2 * (size_t)KK * BB;
  float* CP    = W + o; o += 32 * (size_t)KK * DD;   // aggk partials [2*16][K][D]
  float* CPN   = W + o; o += 4 * (size_t)BB * DD;    // aggn partials [2*2][B][D]
  float* AGGN1 = W + o; o += (size_t)BB * DD;
  float* AGGK1 = W + o; o += (size_t)KK * DD;
  float* RS2   = W + o; o += 2 * KK;
  float* CPS   = W + o; o += 2 * 131072;
  float* SQ2   = W + o; o += 2 * 512;
  float* CS    = W + o; o += 2 * 256;
  float* LSC   = W + o; o += 2;
  float* LPN   = W + o; o += 1024;
  float* LPK   = W + o; o += 128;
  float* PART_K = W + o; o += 256;
  float* SQPN  = W + o; o += 2 * 4096;
  float* SQPK  = W + o; o += 2 * 512;

  float* out = (float*)d_out;
  float* outAssign = out;
  float* outAggn2  = out + BB;
  float* outAggk2  = out + BB + (size_t)BB * DD;
  float* outLoss   = out + BB + (size_t)BB * DD + (size_t)KK * DD;

  u32 kq0, kq1, kc[2][2];
  tf2x32(0u, 42u, 0u, 0u, kq0, kq1);
  tf2x32(0u, 42u, 0u, 1u, kc[0][0], kc[0][1]);
  tf2x32(0u, 42u, 0u, 2u, kc[1][0], kc[1][1]);
  u32 sub[2][3][2];
  for (int br = 0; br < 2; br++)
    for (int t = 0; t < 3; t++)
      tf2x32(kc[br][0], kc[br][1], 0u, (u32)t, sub[br][t][0], sub[br][t][1]);

  // stats chain
  k_sumsq<<<256, 256, 0, stream>>>(queue_k, QQ * DD, PART_K);
  k_stats<<<dim3(512, 2), 256, 0, stream>>>(queue_n, queue_k, PART_K, CPS, SQ2, kq0, kq1);
  k_finalize_csum<<<dim3(256, 2), 256, 0, stream>>>(CPS, CS);
  k_finalize_lsc<<<2, 256, 0, stream>>>(SQ2, LSC);

  // batched branch pipeline (all GEMMs >= 4 blocks/CU)
  k_gemm_nt<<<dim3(KK / 64, BB / 64, 2), 256, 0, stream>>>(feat0, feat1, ctx0, ctx1, T, KK);
  k_softmax_assign<<<2 * BB, 256, 0, stream>>>(T, Yb, outAssign,
      sub[0][0][0], sub[0][0][1], sub[1][0][0], sub[1][0][1], sub[0][1][0], sub[0][1][1]);
  k_binary<<<2048, 256, 0, stream>>>(T, BIN,
      sub[0][2][0], sub[0][2][1], sub[1][2][0], sub[1][2][1]);
  k_rowsum<<<2 * KK, 256, 0, stream>>>(BIN, RS2);
  k_gemm_aggn<<<dim3(DD / 64, BB / 64, 4), 256, 0, stream>>>(Yb, ctx0, ctx1, CPN);
  k_reduce_n<<<dim3(BB * DD / 256, 2), 256, 0, stream>>>(CPN, AGGN1, outAggn2, SQPN);
  k_gemm_aggk<<<dim3(DD / 64, KK / 64, 32), 256, 0, stream>>>(BIN, feat0, feat1, CP);
  k_reduce_div<<<dim3(KK * DD / 256, 2), 256, 0, stream>>>(CP, RS2, AGGK1, outAggk2, SQPK);
  k_scale_cvt<<<dim3(BB * DD / 1024, 2), 256, 0, stream>>>(AGGN1, outAggn2, SQPN, 4096, BB * DD);
  k_scale_cvt<<<dim3(KK * DD / 1024, 2), 256, 0, stream>>>(AGGK1, outAggk2, SQPK, 512, KK * DD);

  // Taylor-collapsed losses
  k_loss_row<<<1152, 256, 0, stream>>>(AGGN1, outAggn2, AGGK1, outAggk2, CS, LSC, LPN, LPK);
  k_loss_final<<<1, 256, 0, stream>>>(LPN, BB / 4, 1.0f / BB, LPK, KK / 4, 1.0f / KK, outLoss);
}

// Round 17
// 216.177 us; speedup vs baseline: 1.3363x; 1.0557x over previous
//
#include <hip/hip_runtime.h>
#include <stdint.h>
#include <math.h>

typedef unsigned int u32;

#define BB 4096
#define DD 256
#define KK 512
#define LL 32768
#define QQ 8192

// ---------------- Threefry2x32 (JAX-exact, 20 rounds) ----------------
__host__ __device__ inline void tf2x32(u32 k0, u32 k1, u32 c0, u32 c1, u32& o0, u32& o1) {
  u32 ks2 = k0 ^ k1 ^ 0x1BD11BDAu;
  u32 x0 = c0 + k0, x1 = c1 + k1;
#define TF_R(r) { x0 += x1; x1 = ((x1 << (r)) | (x1 >> (32 - (r)))); x1 ^= x0; }
  TF_R(13) TF_R(15) TF_R(26) TF_R(6)
  x0 += k1; x1 += ks2 + 1u;
  TF_R(17) TF_R(29) TF_R(16) TF_R(24)
  x0 += ks2; x1 += k0 + 2u;
  TF_R(13) TF_R(15) TF_R(26) TF_R(6)
  x0 += k0; x1 += k1 + 3u;
  TF_R(17) TF_R(29) TF_R(16) TF_R(24)
  x0 += k1; x1 += ks2 + 4u;
  TF_R(13) TF_R(15) TF_R(26) TF_R(6)
  x0 += ks2; x1 += k0 + 5u;
#undef TF_R
  o0 = x0; o1 = x1;
}

__device__ inline u32 rbits32(u32 k0, u32 k1, u32 i) {
  u32 a, b;
  tf2x32(k0, k1, 0u, i, a, b);
  return a ^ b;
}

__device__ inline float u01f(u32 bits) {
  return __uint_as_float(0x3f800000u | (bits >> 9)) - 1.0f;
}

// f64-log gumbel: argmax-critical path only (bit-stable vs CPU libm)
__device__ inline float gumbel_at(u32 k0, u32 k1, u32 i) {
  float f = u01f(rbits32(k0, k1, i));
  float u = fmaxf(1e-20f, f + 1e-20f);
  float l1 = (float)log((double)u);
  float l2 = (float)log((double)(-l1));
  return -l2;
}

// fast f32 gumbel: continuous-output paths (y1 softmax)
__device__ inline float gumbel_f32(u32 k0, u32 k1, u32 i) {
  float f = u01f(rbits32(k0, k1, i));
  float u = fmaxf(1e-20f, f + 1e-20f);
  float l1 = __logf(u);
  return -__logf(-l1);
}

// XLA f32 ErfInv (Giles polynomial)
__device__ inline float erfinv32(float x) {
  float w = -log1pf(-x * x);
  float p;
  if (w < 5.0f) {
    w -= 2.5f;
    p = 2.81022636e-08f;
    p = fmaf(p, w, 3.43273939e-07f);
    p = fmaf(p, w, -3.5233877e-06f);
    p = fmaf(p, w, -4.39150654e-06f);
    p = fmaf(p, w, 0.00021858087f);
    p = fmaf(p, w, -0.00125372503f);
    p = fmaf(p, w, -0.00417768164f);
    p = fmaf(p, w, 0.246640727f);
    p = fmaf(p, w, 1.50140941f);
  } else {
    w = sqrtf(w) - 3.0f;
    p = -0.000200214257f;
    p = fmaf(p, w, 0.000100950558f);
    p = fmaf(p, w, 0.00134934322f);
    p = fmaf(p, w, -0.00367342844f);
    p = fmaf(p, w, 0.00573950773f);
    p = fmaf(p, w, -0.0076224613f);
    p = fmaf(p, w, 0.00943887047f);
    p = fmaf(p, w, 1.00167406f);
    p = fmaf(p, w, 2.83297682f);
  }
  return p * x;
}

// ---------------- queue_k raw sumsq (for sk) ----------------
__global__ __launch_bounds__(256)
void k_sumsq(const float* __restrict__ x, int n, float* __restrict__ partial) {
  __shared__ float sm[256];
  float s = 0.0f;
  for (int i = blockIdx.x * 256 + threadIdx.x; i < n; i += gridDim.x * 256) {
    float v = x[i]; s = fmaf(v, v, s);
  }
  sm[threadIdx.x] = s; __syncthreads();
  for (int off = 128; off > 0; off >>= 1) {
    if (threadIdx.x < off) sm[threadIdx.x] += sm[threadIdx.x + off];
    __syncthreads();
  }
  if (threadIdx.x == 0) partial[blockIdx.x] = sm[0];
}

// ---------------- fused stats: z=0 queue_n (64 rows/blk), z=1 constructed queue ----------------
__global__ __launch_bounds__(256)
void k_stats(const float* __restrict__ qn, const float* __restrict__ qk_in,
             const float* __restrict__ partK,
             float* __restrict__ colpart, float* __restrict__ sqpart,
             u32 kqa, u32 kqb) {
  __shared__ float smc[4][256];
  __shared__ float sm[256];
  int tid = threadIdx.x, g = tid >> 6, l = tid & 63;
  int z = blockIdx.y;
  float4 ca = {0.f, 0.f, 0.f, 0.f};
  float ss = 0.0f;
  if (z == 0) {
    int base = blockIdx.x * 64;
    for (int j = base + g; j < base + 64; j += 4) {
      float4 v = *(const float4*)(qn + (size_t)j * 256 + l * 4);
      ca.x += v.x; ca.y += v.y; ca.z += v.z; ca.w += v.w;
      ss = fmaf(v.x, v.x, ss); ss = fmaf(v.y, v.y, ss);
      ss = fmaf(v.z, v.z, ss); ss = fmaf(v.w, v.w, ss);
    }
  } else {
    sm[tid] = partK[tid]; __syncthreads();
    for (int off = 128; off > 0; off >>= 1) {
      if (tid < off) sm[tid] += sm[tid + off];
      __syncthreads();
    }
    float sk = (float)(1.0 / sqrt((double)fmaxf(sm[0], 1e-12f)));
    __syncthreads();
    const float lo = -0.99999994f;
    int base = blockIdx.x * 16;
    for (int j = base + g; j < base + 16; j += 4) {
      int i0 = j * 256 + l * 4;
      float4 v = *(const float4*)(qk_in + i0);
      float vin[4] = {v.x, v.y, v.z, v.w};
      float valv[4];
#pragma unroll
      for (int e = 0; e < 4; e++) {
        float qk = vin[e] * sk;
        float f = u01f(rbits32(kqa, kqb, (u32)(i0 + e)));
        float u = fmaxf(lo, f * 2.0f + lo);
        float nv = 1.41421354f * erfinv32(u);
        float t = qk + 0.1f * nv;
        valv[e] = t + qk;
        ss = fmaf(valv[e], valv[e], ss);
      }
      ca.x += valv[0]; ca.y += valv[1]; ca.z += valv[2]; ca.w += valv[3];
    }
  }
  smc[g][l * 4 + 0] = ca.x; smc[g][l * 4 + 1] = ca.y;
  smc[g][l * 4 + 2] = ca.z; smc[g][l * 4 + 3] = ca.w;
  sm[tid] = ss; __syncthreads();
  colpart[(size_t)z * 131072 + blockIdx.x * 256 + tid] =
      (smc[0][tid] + smc[1][tid]) + (smc[2][tid] + smc[3][tid]);
  for (int off = 128; off > 0; off >>= 1) {
    if (tid < off) sm[tid] += sm[tid + off];
    __syncthreads();
  }
  if (tid == 0) sqpart[z * 512 + blockIdx.x] = sm[0];
}

// merged finalize: grid (257, 2). x<256: csum col; x==256: lsc scalar.
__global__ __launch_bounds__(256)
void k_finalize(const float* __restrict__ colpart, const float* __restrict__ sqpart,
                float* __restrict__ csum, float* __restrict__ lscOut) {
  __shared__ float sm[256];
  int z = blockIdx.y, t = threadIdx.x;
  if (blockIdx.x < 256) {
    int d = blockIdx.x;
    const float* cp = colpart + (size_t)z * 131072;
    float a = cp[(size_t)t * 256 + d] + cp[(size_t)(t + 256) * 256 + d];
    sm[t] = a; __syncthreads();
    for (int off = 128; off > 0; off >>= 1) {
      if (t < off) sm[t] += sm[t + off];
      __syncthreads();
    }
    if (t == 0) csum[z * 256 + d] = sm[0];
  } else {
    const float* sq = sqpart + z * 512;
    float a = sq[t] + sq[t + 256];
    sm[t] = a; __syncthreads();
    for (int off = 128; off > 0; off >>= 1) {
      if (t < off) sm[t] += sm[t + off];
      __syncthreads();
    }
    if (t == 0) {
      float sr = (float)(1.0 / sqrt((double)fmaxf(sm[0], 1e-12f)));
      lscOut[z] = sr / 0.07f;
    }
  }
}

// ---------------- knT GEMM (64x64, 4x4) + fused stochastic binary ----------------
// T values and RNG indices bit-identical to prior rounds; binary computed from
// the register tile via padded-LDS transpose (saves a 33.5MB T re-read + launch).
__global__ __launch_bounds__(256)
void k_gemm_nt(const float* __restrict__ A0, const float* __restrict__ A1,
               const float* __restrict__ B0, const float* __restrict__ B1,
               float* __restrict__ C, float* __restrict__ BIN,
               u32 k3a0, u32 k3b0, u32 k3a1, u32 k3b1) {
  __shared__ float As[16][68], Bs[16][68];
  __shared__ float Ts[64][65];
  int tid = threadIdx.x;
  int tx = tid & 15, ty = tid >> 4;
  int rowBase = blockIdx.y * 64, colBase = blockIdx.x * 64;
  int br = blockIdx.z;
  const float* A = br ? A1 : A0;
  const float* Bm = br ? B1 : B0;
  u32 k3a = br ? k3a1 : k3a0, k3b = br ? k3b1 : k3b0;
  float* Cd = C + (size_t)br * BB * KK;
  float* Bd = BIN + (size_t)br * KK * BB;
  float c[4][4] = {};
  for (int kt = 0; kt < 256; kt += 16) {
#pragma unroll
    for (int q = 0; q < 4; q++) {
      int idx = tid + 256 * q;
      int kkx = idx & 15, rr = idx >> 4;
      As[kkx][rr] = A[(size_t)(rowBase + rr) * 256 + kt + kkx];
      Bs[kkx][rr] = Bm[(size_t)(colBase + rr) * 256 + kt + kkx];
    }
    __syncthreads();
#pragma unroll
    for (int kx = 0; kx < 16; kx++) {
      float4 a4 = *(const float4*)&As[kx][ty * 4];
      float4 b4 = *(const float4*)&Bs[kx][tx * 4];
      float av[4] = {a4.x, a4.y, a4.z, a4.w};
      float bv[4] = {b4.x, b4.y, b4.z, b4.w};
#pragma unroll
      for (int r = 0; r < 4; r++)
#pragma unroll
        for (int q = 0; q < 4; q++)
          c[r][q] = fmaf(av[r], bv[q], c[r][q]);
    }
    __syncthreads();
  }
#pragma unroll
  for (int r = 0; r < 4; r++)
#pragma unroll
    for (int q = 0; q < 4; q++) {
      Cd[(size_t)(rowBase + ty * 4 + r) * KK + colBase + tx * 4 + q] = c[r][q];
      Ts[ty * 4 + r][tx * 4 + q] = c[r][q];
    }
  __syncthreads();
  // binary epilogue: 16 elems/thread, transposed; coalesced BIN writes
#pragma unroll
  for (int p = 0; p < 16; p++) {
    int idx = p * 256 + tid;
    int kl = idx >> 6, bl = idx & 63;
    float x = Ts[bl][kl];
    float prob = 1.0f / (1.0f + expf(-x));
    int k = colBase + kl, b = rowBase + bl;
    u32 i = (u32)(k * BB + b);
    float eps = u01f(rbits32(k3a, k3b, i));
    Bd[(size_t)k * BB + b] = (prob > eps) ? 1.0f : 0.0f;
  }
}

// agg_n partials = Y @ ctx (NN), split-K S=2; grid (DD/64, BB/64, 4); z = br*2+s
__global__ __launch_bounds__(256)
void k_gemm_aggn(const float* __restrict__ Yb, const float* __restrict__ B0,
                 const float* __restrict__ B1, float* __restrict__ CPN) {
  __shared__ float As[16][68], Bs[16][68];
  int tid = threadIdx.x;
  int tx = tid & 15, ty = tid >> 4;
  int rowBase = blockIdx.y * 64, colBase = blockIdx.x * 64;
  int br = blockIdx.z >> 1, s = blockIdx.z & 1;
  const float* A = Yb + (size_t)br * BB * KK;
  const float* Bm = br ? B1 : B0;
  int k0 = s * 256;
  float c[4][4] = {};
  for (int kt = k0; kt < k0 + 256; kt += 16) {
#pragma unroll
    for (int q = 0; q < 4; q++) {
      int idx = tid + 256 * q;
      int kkx = idx & 15, rr = idx >> 4;
      As[kkx][rr] = A[(size_t)(rowBase + rr) * KK + kt + kkx];
      int kk = (tid >> 6) * 4 + q;
      int jj = tid & 63;
      Bs[kk][jj] = Bm[(size_t)(kt + kk) * DD + colBase + jj];
    }
    __syncthreads();
#pragma unroll
    for (int kx = 0; kx < 16; kx++) {
      float4 a4 = *(const float4*)&As[kx][ty * 4];
      float4 b4 = *(const float4*)&Bs[kx][tx * 4];
      float av[4] = {a4.x, a4.y, a4.z, a4.w};
      float bv[4] = {b4.x, b4.y, b4.z, b4.w};
#pragma unroll
      for (int r = 0; r < 4; r++)
#pragma unroll
        for (int q = 0; q < 4; q++)
          c[r][q] = fmaf(av[r], bv[q], c[r][q]);
    }
    __syncthreads();
  }
  float* dst = CPN + (size_t)blockIdx.z * BB * DD;
#pragma unroll
  for (int r = 0; r < 4; r++)
#pragma unroll
    for (int q = 0; q < 4; q++)
      dst[(size_t)(rowBase + ty * 4 + r) * DD + colBase + tx * 4 + q] = c[r][q];
}

// agg_k partials = BIN @ feat (NN), split-K S=16; grid (DD/64, KK/64, 32); z = br*16+s
__global__ __launch_bounds__(256)
void k_gemm_aggk(const float* __restrict__ BIN, const float* __restrict__ B0,
                 const float* __restrict__ B1, float* __restrict__ CP) {
  __shared__ float As[16][68], Bs[16][68];
  int tid = threadIdx.x;
  int tx = tid & 15, ty = tid >> 4;
  int rowBase = blockIdx.y * 64, colBase = blockIdx.x * 64;
  int br = blockIdx.z >> 4, s = blockIdx.z & 15;
  const float* A = BIN + (size_t)br * KK * BB;
  const float* Bm = br ? B1 : B0;
  int k0 = s * 256;
  float c[4][4] = {};
  for (int kt = k0; kt < k0 + 256; kt += 16) {
#pragma unroll
    for (int q = 0; q < 4; q++) {
      int idx = tid + 256 * q;
      int kkx = idx & 15, rr = idx >> 4;
      As[kkx][rr] = A[(size_t)(rowBase + rr) * BB + kt + kkx];
      int kk = (tid >> 6) * 4 + q;
      int jj = tid & 63;
      Bs[kk][jj] = Bm[(size_t)(kt + kk) * DD + colBase + jj];
    }
    __syncthreads();
#pragma unroll
    for (int kx = 0; kx < 16; kx++) {
      float4 a4 = *(const float4*)&As[kx][ty * 4];
      float4 b4 = *(const float4*)&Bs[kx][tx * 4];
      float av[4] = {a4.x, a4.y, a4.z, a4.w};
      float bv[4] = {b4.x, b4.y, b4.z, b4.w};
#pragma unroll
      for (int r = 0; r < 4; r++)
#pragma unroll
        for (int q = 0; q < 4; q++)
          c[r][q] = fmaf(av[r], bv[q], c[r][q]);
    }
    __syncthreads();
  }
  float* dst = CP + (size_t)blockIdx.z * KK * DD;
#pragma unroll
  for (int r = 0; r < 4; r++)
#pragma unroll
    for (int q = 0; q < 4; q++)
      dst[(size_t)(rowBase + ty * 4 + r) * DD + colBase + tx * 4 + q] = c[r][q];
}

// merged reduce: grid (4608, 2). x<4096: aggn S=2 sum; else aggk S=16 sum + div.
__global__ __launch_bounds__(256)
void k_reduce(const float* __restrict__ CPN, const float* __restrict__ CP,
              const float* __restrict__ rs2,
              float* __restrict__ N0, float* __restrict__ N1,
              float* __restrict__ K0, float* __restrict__ K1,
              float* __restrict__ sqpN, float* __restrict__ sqpK) {
  __shared__ float sq[256];
  int tid = threadIdx.x, br = blockIdx.y;
  float v;
  if (blockIdx.x < 4096) {
    int i = blockIdx.x * 256 + tid;
    const int MN = BB * DD;
    v = CPN[(size_t)(2 * br) * MN + i] + CPN[(size_t)(2 * br + 1) * MN + i];
    (br ? N1 : N0)[i] = v;
  } else {
    int i = (blockIdx.x - 4096) * 256 + tid;
    const int MN = KK * DD;
    const float* cp = CP + (size_t)br * 16 * MN;
    float s = 0.0f;
    for (int t = 0; t < 16; t++) s += cp[(size_t)t * MN + i];
    v = s / (rs2[br * KK + (i >> 8)] + 1e-8f);
    (br ? K1 : K0)[i] = v;
  }
  sq[tid] = v * v; __syncthreads();
  for (int off = 128; off > 0; off >>= 1) {
    if (tid < off) sq[tid] += sq[tid + off];
    __syncthreads();
  }
  if (tid == 0) {
    if (blockIdx.x < 4096) sqpN[br * 4096 + blockIdx.x] = sq[0];
    else sqpK[br * 512 + (blockIdx.x - 4096)] = sq[0];
  }
}

// merged scale: grid (1152, 2). x<1024: aggn; else aggk.
__global__ __launch_bounds__(256)
void k_scale(float* __restrict__ N0, float* __restrict__ N1,
             float* __restrict__ K0, float* __restrict__ K1,
             const float* __restrict__ sqpN, const float* __restrict__ sqpK) {
  __shared__ float sm[256];
  int tid = threadIdx.x, br = blockIdx.y;
  int isK = (blockIdx.x >= 1024);
  const float* sq = isK ? (sqpK + br * 512) : (sqpN + br * 4096);
  int np = isK ? 512 : 4096;
  float a = 0.0f;
  for (int i = tid; i < np; i += 256) a += sq[i];
  sm[tid] = a; __syncthreads();
  for (int off = 128; off > 0; off >>= 1) {
    if (tid < off) sm[tid] += sm[tid + off];
    __syncthreads();
  }
  float f = (float)(1.0 / sqrt((double)fmaxf(sm[0], 1e-12f)));
  float* data = isK ? (br ? K1 : K0) : (br ? N1 : N0);
  int xb = isK ? (blockIdx.x - 1024) : blockIdx.x;
  int i = (xb * 256 + tid) * 4;
  float4 v = *(const float4*)(data + i);
  v.x *= f; v.y *= f; v.z *= f; v.w *= f;
  *(float4*)(data + i) = v;
}

// ---------------- softmax(y1) + hard argmax(y2), batched over branches ----------------
__global__ __launch_bounds__(256)
void k_softmax_assign(const float* __restrict__ T, float* __restrict__ Y,
                      float* __restrict__ assignOut,
                      u32 g1a0, u32 g1b0, u32 g1a1, u32 g1b1, u32 g2a, u32 g2b) {
  __shared__ float smA[4], smS[4], smM2[4], smS2[4], smV[4];
  __shared__ int smI[4];
  int bid = blockIdx.x, tid = threadIdx.x;
  int br = bid >> 12, b = bid & 4095;
  u32 g1a = br ? g1a1 : g1a0, g1b = br ? g1b1 : g1b0;
  const float* knT = T + (size_t)br * BB * KK;
  float* Yd = Y + (size_t)br * BB * KK;
  int lane = tid & 63, wid = tid >> 6;
  int i0 = b * KK + tid, i1 = i0 + 256;
  float x0 = knT[i0], x1 = knT[i1];

  float z0 = x0 + gumbel_f32(g1a, g1b, (u32)i0);
  float z1 = x1 + gumbel_f32(g1a, g1b, (u32)i1);
  float wm = fmaxf(z0, z1);
#pragma unroll
  for (int off = 1; off < 64; off <<= 1) wm = fmaxf(wm, __shfl_xor(wm, off, 64));
  if (lane == 0) smA[wid] = wm;
  __syncthreads();
  float m = fmaxf(fmaxf(smA[0], smA[1]), fmaxf(smA[2], smA[3]));
  float e0 = expf(z0 - m), e1 = expf(z1 - m);
  float ws = e0 + e1;
#pragma unroll
  for (int off = 1; off < 64; off <<= 1) ws += __shfl_xor(ws, off, 64);
  if (lane == 0) smS[wid] = ws;
  __syncthreads();
  float s = (smS[0] + smS[1]) + (smS[2] + smS[3]);
  Yd[i0] = e0 / s;
  Yd[i1] = e1 / s;

  if (br == 0) {
    float w0 = x0 + gumbel_at(g2a, g2b, (u32)i0);
    float w1 = x1 + gumbel_at(g2a, g2b, (u32)i1);
    float wm2 = fmaxf(w0, w1);
#pragma unroll
    for (int off = 1; off < 64; off <<= 1) wm2 = fmaxf(wm2, __shfl_xor(wm2, off, 64));
    if (lane == 0) smM2[wid] = wm2;
    __syncthreads();
    float m2 = fmaxf(fmaxf(smM2[0], smM2[1]), fmaxf(smM2[2], smM2[3]));
    float f0 = expf(w0 - m2), f1 = expf(w1 - m2);
    float ws2 = f0 + f1;
#pragma unroll
    for (int off = 1; off < 64; off <<= 1) ws2 += __shfl_xor(ws2, off, 64);
    if (lane == 0) smS2[wid] = ws2;
    __syncthreads();
    float s2 = (smS2[0] + smS2[1]) + (smS2[2] + smS2[3]);
    float y0 = f0 / s2, y1v = f1 / s2;
    float bv; int bi;
    if (y1v > y0) { bv = y1v; bi = tid + 256; } else { bv = y0; bi = tid; }
#pragma unroll
    for (int off = 1; off < 64; off <<= 1) {
      float ov = __shfl_xor(bv, off, 64);
      int oi = __shfl_xor(bi, off, 64);
      if (ov > bv || (ov == bv && oi < bi)) { bv = ov; bi = oi; }
    }
    if (lane == 0) { smV[wid] = bv; smI[wid] = bi; }
    __syncthreads();
    if (tid == 0) {
      float cv = smV[0]; int ci = smI[0];
#pragma unroll
      for (int t = 1; t < 4; t++) {
        if (smV[t] > cv || (smV[t] == cv && smI[t] < ci)) { cv = smV[t]; ci = smI[t]; }
      }
      assignOut[b] = (float)ci;
    }
  }
}

// ---------------- row sums of BIN: one block per (br,k) row, coalesced ----------------
__global__ __launch_bounds__(256)
void k_rowsum(const float* __restrict__ BIN, float* __restrict__ rs2) {
  __shared__ float sm[4];
  int row = blockIdx.x;
  const float* src = BIN + (size_t)row * BB;
  int tid = threadIdx.x, l = tid & 63, w = tid >> 6;
  float s = 0.0f;
#pragma unroll
  for (int p = 0; p < 4; p++) {
    float4 v = *(const float4*)(src + (p * 256 + tid) * 4);
    s += (v.x + v.y) + (v.z + v.w);
  }
#pragma unroll
  for (int off = 1; off < 64; off <<= 1) s += __shfl_xor(s, off, 64);
  if (l == 0) sm[w] = s;
  __syncthreads();
  if (tid == 0) rs2[row] = (sm[0] + sm[1]) + (sm[2] + sm[3]);
}

// ---------------- Taylor-collapsed InfoNCE loss, batched (1152 blocks) ----------------
__global__ __launch_bounds__(256)
void k_loss_row(const float* __restrict__ QN, const float* __restrict__ KPN,
                const float* __restrict__ QK, const float* __restrict__ KPK,
                const float* __restrict__ csum, const float* __restrict__ lscp,
                float* __restrict__ LPN, float* __restrict__ LPK) {
  __shared__ float pt[4];
  int w = threadIdx.x >> 6, l = threadIdx.x & 63;
  int bid = blockIdx.x;
  int isK = (bid >= 1024);
  int rb = isK ? (bid - 1024) : bid;
  const float* Q  = isK ? QK : QN;
  const float* KP = isK ? KPK : KPN;
  const float* cs4 = csum + (isK ? 256 : 0);
  float Lc = isK ? (float)QQ : (float)LL;
  float lsc = lscp[isK ? 1 : 0];
  int r = rb * 4 + w;
  float4 q = *(const float4*)(Q + (size_t)r * 256 + l * 4);
  float4 kp = *(const float4*)(KP + (size_t)r * 256 + l * 4);
  float4 cs = *(const float4*)(cs4 + l * 4);
  float d1 = q.x * kp.x + q.y * kp.y + q.z * kp.z + q.w * kp.w;
  float d2 = q.x * cs.x + q.y * cs.y + q.z * cs.z + q.w * cs.w;
#pragma unroll
  for (int off = 1; off < 64; off <<= 1) {
    d1 += __shfl_xor(d1, off, 64);
    d2 += __shfl_xor(d2, off, 64);
  }
  if (l == 0) {
    float z0 = d1 / 0.07f;
    double S = (double)Lc + (double)expf(z0) + (double)(lsc * d2);
    pt[w] = (float)(log(S)) - z0;
  }
  __syncthreads();
  if (threadIdx.x == 0) {
    float v = (pt[0] + pt[1]) + (pt[2] + pt[3]);
    if (isK) LPK[rb] = v; else LPN[rb] = v;
  }
}

__global__ __launch_bounds__(256)
void k_loss_final(const float* __restrict__ LPN, int nN, float invMN,
                  const float* __restrict__ LPK, int nK, float invMK,
                  float* __restrict__ outLoss) {
  __shared__ float sm[256];
  int tid = threadIdx.x;
  float a = 0.0f;
  for (int i = tid; i < nN; i += 256) a += LPN[i];
  sm[tid] = a; __syncthreads();
  for (int off = 128; off > 0; off >>= 1) {
    if (tid < off) sm[tid] += sm[tid + off];
    __syncthreads();
  }
  float lossN = sm[0] * invMN;
  __syncthreads();
  float b = 0.0f;
  for (int i = tid; i < nK; i += 256) b += LPK[i];
  sm[tid] = b; __syncthreads();
  for (int off = 128; off > 0; off >>= 1) {
    if (tid < off) sm[tid] += sm[tid + off];
    __syncthreads();
  }
  if (tid == 0) outLoss[0] = lossN + sm[0] * invMK;
}

// ---------------- launch ----------------
extern "C" void kernel_launch(void* const* d_in, const int* in_sizes, int n_in,
                              void* d_out, int out_size, void* d_ws, size_t ws_size,
                              hipStream_t stream) {
  const float* feat0 = (const float*)d_in[0];
  const float* feat1 = (const float*)d_in[1];
  const float* ctx0  = (const float*)d_in[2];
  const float* ctx1  = (const float*)d_in[3];
  const float* queue_n = (const float*)d_in[4];
  const float* queue_k = (const float*)d_in[5];

  float* W = (float*)d_ws;
  size_t o = 0;
  float* T     = W + o; o += 2 * (size_t)BB * KK;
  float* Yb    = W + o; o += 2 * (size_t)BB * KK;
  float* BIN   = W + o; o += 2 * (size_t)KK * BB;
  float* CP    = W + o; o += 32 * (size_t)KK * DD;
  float* CPN   = W + o; o += 4 * (size_t)BB * DD;
  float* AGGN1 = W + o; o += (size_t)BB * DD;
  float* AGGK1 = W + o; o += (size_t)KK * DD;
  float* RS2   = W + o; o += 2 * KK;
  float* CPS   = W + o; o += 2 * 131072;
  float* SQ2   = W + o; o += 2 * 512;
  float* CS    = W + o; o += 2 * 256;
  float* LSC   = W + o; o += 2;
  float* LPN   = W + o; o += 1024;
  float* LPK   = W + o; o += 128;
  float* PART_K = W + o; o += 256;
  float* SQPN  = W + o; o += 2 * 4096;
  float* SQPK  = W + o; o += 2 * 512;

  float* out = (float*)d_out;
  float* outAssign = out;
  float* outAggn2  = out + BB;
  float* outAggk2  = out + BB + (size_t)BB * DD;
  float* outLoss   = out + BB + (size_t)BB * DD + (size_t)KK * DD;

  u32 kq0, kq1, kc[2][2];
  tf2x32(0u, 42u, 0u, 0u, kq0, kq1);
  tf2x32(0u, 42u, 0u, 1u, kc[0][0], kc[0][1]);
  tf2x32(0u, 42u, 0u, 2u, kc[1][0], kc[1][1]);
  u32 sub[2][3][2];
  for (int br = 0; br < 2; br++)
    for (int t = 0; t < 3; t++)
      tf2x32(kc[br][0], kc[br][1], 0u, (u32)t, sub[br][t][0], sub[br][t][1]);

  // stats chain
  k_sumsq<<<256, 256, 0, stream>>>(queue_k, QQ * DD, PART_K);
  k_stats<<<dim3(512, 2), 256, 0, stream>>>(queue_n, queue_k, PART_K, CPS, SQ2, kq0, kq1);
  k_finalize<<<dim3(257, 2), 256, 0, stream>>>(CPS, SQ2, CS, LSC);

  // batched branch pipeline
  k_gemm_nt<<<dim3(KK / 64, BB / 64, 2), 256, 0, stream>>>(
      feat0, feat1, ctx0, ctx1, T, BIN,
      sub[0][2][0], sub[0][2][1], sub[1][2][0], sub[1][2][1]);
  k_softmax_assign<<<2 * BB, 256, 0, stream>>>(T, Yb, outAssign,
      sub[0][0][0], sub[0][0][1], sub[1][0][0], sub[1][0][1], sub[0][1][0], sub[0][1][1]);
  k_rowsum<<<2 * KK, 256, 0, stream>>>(BIN, RS2);
  k_gemm_aggn<<<dim3(DD / 64, BB / 64, 4), 256, 0, stream>>>(Yb, ctx0, ctx1, CPN);
  k_gemm_aggk<<<dim3(DD / 64, KK / 64, 32), 256, 0, stream>>>(BIN, feat0, feat1, CP);
  k_reduce<<<dim3(4608, 2), 256, 0, stream>>>(CPN, CP, RS2, AGGN1, outAggn2,
                                              AGGK1, outAggk2, SQPN, SQPK);
  k_scale<<<dim3(1152, 2), 256, 0, stream>>>(AGGN1, outAggn2, AGGK1, outAggk2, SQPN, SQPK);

  // Taylor-collapsed losses
  k_loss_row<<<1152, 256, 0, stream>>>(AGGN1, outAggn2, AGGK1, outAggk2, CS, LSC, LPN, LPK);
  k_loss_final<<<1, 256, 0, stream>>>(LPN, BB / 4, 1.0f / BB, LPK, KK / 4, 1.0f / KK, outLoss);
}

// Round 18
// 208.166 us; speedup vs baseline: 1.3878x; 1.0385x over previous
//
#include <hip/hip_runtime.h>
#include <stdint.h>
#include <math.h>

typedef unsigned int u32;

#define BB 4096
#define DD 256
#define KK 512
#define LL 32768
#define QQ 8192

// ---------------- Threefry2x32 (JAX-exact, 20 rounds) ----------------
__host__ __device__ inline void tf2x32(u32 k0, u32 k1, u32 c0, u32 c1, u32& o0, u32& o1) {
  u32 ks2 = k0 ^ k1 ^ 0x1BD11BDAu;
  u32 x0 = c0 + k0, x1 = c1 + k1;
#define TF_R(r) { x0 += x1; x1 = ((x1 << (r)) | (x1 >> (32 - (r)))); x1 ^= x0; }
  TF_R(13) TF_R(15) TF_R(26) TF_R(6)
  x0 += k1; x1 += ks2 + 1u;
  TF_R(17) TF_R(29) TF_R(16) TF_R(24)
  x0 += ks2; x1 += k0 + 2u;
  TF_R(13) TF_R(15) TF_R(26) TF_R(6)
  x0 += k0; x1 += k1 + 3u;
  TF_R(17) TF_R(29) TF_R(16) TF_R(24)
  x0 += k1; x1 += ks2 + 4u;
  TF_R(13) TF_R(15) TF_R(26) TF_R(6)
  x0 += ks2; x1 += k0 + 5u;
#undef TF_R
  o0 = x0; o1 = x1;
}

__device__ inline u32 rbits32(u32 k0, u32 k1, u32 i) {
  u32 a, b;
  tf2x32(k0, k1, 0u, i, a, b);
  return a ^ b;
}

__device__ inline float u01f(u32 bits) {
  return __uint_as_float(0x3f800000u | (bits >> 9)) - 1.0f;
}

// f64-log gumbel: argmax fallback path (bit-stable vs CPU libm)
__device__ inline float gumbel_at(u32 k0, u32 k1, u32 i) {
  float f = u01f(rbits32(k0, k1, i));
  float u = fmaxf(1e-20f, f + 1e-20f);
  float l1 = (float)log((double)u);
  float l2 = (float)log((double)(-l1));
  return -l2;
}

// fast f32 gumbel: <=~2e-6 abs error (v_log_f32 1ulp relative)
__device__ inline float gumbel_f32(u32 k0, u32 k1, u32 i) {
  float f = u01f(rbits32(k0, k1, i));
  float u = fmaxf(1e-20f, f + 1e-20f);
  float l1 = __logf(u);
  return -__logf(-l1);
}

// XLA f32 ErfInv (Giles polynomial)
__device__ inline float erfinv32(float x) {
  float w = -log1pf(-x * x);
  float p;
  if (w < 5.0f) {
    w -= 2.5f;
    p = 2.81022636e-08f;
    p = fmaf(p, w, 3.43273939e-07f);
    p = fmaf(p, w, -3.5233877e-06f);
    p = fmaf(p, w, -4.39150654e-06f);
    p = fmaf(p, w, 0.00021858087f);
    p = fmaf(p, w, -0.00125372503f);
    p = fmaf(p, w, -0.00417768164f);
    p = fmaf(p, w, 0.246640727f);
    p = fmaf(p, w, 1.50140941f);
  } else {
    w = sqrtf(w) - 3.0f;
    p = -0.000200214257f;
    p = fmaf(p, w, 0.000100950558f);
    p = fmaf(p, w, 0.00134934322f);
    p = fmaf(p, w, -0.00367342844f);
    p = fmaf(p, w, 0.00573950773f);
    p = fmaf(p, w, -0.0076224613f);
    p = fmaf(p, w, 0.00943887047f);
    p = fmaf(p, w, 1.00167406f);
    p = fmaf(p, w, 2.83297682f);
  }
  return p * x;
}

// ---------------- queue_k raw sumsq (for sk) ----------------
__global__ __launch_bounds__(256)
void k_sumsq(const float* __restrict__ x, int n, float* __restrict__ partial) {
  __shared__ float sm[256];
  float s = 0.0f;
  for (int i = blockIdx.x * 256 + threadIdx.x; i < n; i += gridDim.x * 256) {
    float v = x[i]; s = fmaf(v, v, s);
  }
  sm[threadIdx.x] = s; __syncthreads();
  for (int off = 128; off > 0; off >>= 1) {
    if (threadIdx.x < off) sm[threadIdx.x] += sm[threadIdx.x + off];
    __syncthreads();
  }
  if (threadIdx.x == 0) partial[blockIdx.x] = sm[0];
}

// ---------------- fused stats: z=0 queue_n, z=1 constructed queue ----------------
__global__ __launch_bounds__(256)
void k_stats(const float* __restrict__ qn, const float* __restrict__ qk_in,
             const float* __restrict__ partK,
             float* __restrict__ colpart, float* __restrict__ sqpart,
             u32 kqa, u32 kqb) {
  __shared__ float smc[4][256];
  __shared__ float sm[256];
  int tid = threadIdx.x, g = tid >> 6, l = tid & 63;
  int z = blockIdx.y;
  float4 ca = {0.f, 0.f, 0.f, 0.f};
  float ss = 0.0f;
  if (z == 0) {
    int base = blockIdx.x * 64;
    for (int j = base + g; j < base + 64; j += 4) {
      float4 v = *(const float4*)(qn + (size_t)j * 256 + l * 4);
      ca.x += v.x; ca.y += v.y; ca.z += v.z; ca.w += v.w;
      ss = fmaf(v.x, v.x, ss); ss = fmaf(v.y, v.y, ss);
      ss = fmaf(v.z, v.z, ss); ss = fmaf(v.w, v.w, ss);
    }
  } else {
    sm[tid] = partK[tid]; __syncthreads();
    for (int off = 128; off > 0; off >>= 1) {
      if (tid < off) sm[tid] += sm[tid + off];
      __syncthreads();
    }
    float sk = (float)(1.0 / sqrt((double)fmaxf(sm[0], 1e-12f)));
    __syncthreads();
    const float lo = -0.99999994f;
    int base = blockIdx.x * 16;
    for (int j = base + g; j < base + 16; j += 4) {
      int i0 = j * 256 + l * 4;
      float4 v = *(const float4*)(qk_in + i0);
      float vin[4] = {v.x, v.y, v.z, v.w};
      float valv[4];
#pragma unroll
      for (int e = 0; e < 4; e++) {
        float qk = vin[e] * sk;
        float f = u01f(rbits32(kqa, kqb, (u32)(i0 + e)));
        float u = fmaxf(lo, f * 2.0f + lo);
        float nv = 1.41421354f * erfinv32(u);
        float t = qk + 0.1f * nv;
        valv[e] = t + qk;
        ss = fmaf(valv[e], valv[e], ss);
      }
      ca.x += valv[0]; ca.y += valv[1]; ca.z += valv[2]; ca.w += valv[3];
    }
  }
  smc[g][l * 4 + 0] = ca.x; smc[g][l * 4 + 1] = ca.y;
  smc[g][l * 4 + 2] = ca.z; smc[g][l * 4 + 3] = ca.w;
  sm[tid] = ss; __syncthreads();
  colpart[(size_t)z * 131072 + blockIdx.x * 256 + tid] =
      (smc[0][tid] + smc[1][tid]) + (smc[2][tid] + smc[3][tid]);
  for (int off = 128; off > 0; off >>= 1) {
    if (tid < off) sm[tid] += sm[tid + off];
    __syncthreads();
  }
  if (tid == 0) sqpart[z * 512 + blockIdx.x] = sm[0];
}

// merged finalize: grid (257, 2). x<256: csum col; x==256: lsc scalar.
__global__ __launch_bounds__(256)
void k_finalize(const float* __restrict__ colpart, const float* __restrict__ sqpart,
                float* __restrict__ csum, float* __restrict__ lscOut) {
  __shared__ float sm[256];
  int z = blockIdx.y, t = threadIdx.x;
  if (blockIdx.x < 256) {
    int d = blockIdx.x;
    const float* cp = colpart + (size_t)z * 131072;
    float a = cp[(size_t)t * 256 + d] + cp[(size_t)(t + 256) * 256 + d];
    sm[t] = a; __syncthreads();
    for (int off = 128; off > 0; off >>= 1) {
      if (t < off) sm[t] += sm[t + off];
      __syncthreads();
    }
    if (t == 0) csum[z * 256 + d] = sm[0];
  } else {
    const float* sq = sqpart + z * 512;
    float a = sq[t] + sq[t + 256];
    sm[t] = a; __syncthreads();
    for (int off = 128; off > 0; off >>= 1) {
      if (t < off) sm[t] += sm[t + off];
      __syncthreads();
    }
    if (t == 0) {
      float sr = (float)(1.0 / sqrt((double)fmaxf(sm[0], 1e-12f)));
      lscOut[z] = sr / 0.07f;
    }
  }
}

// ---------------- knT GEMM (64x64, 4x4) + fused stochastic binary ----------------
__global__ __launch_bounds__(256)
void k_gemm_nt(const float* __restrict__ A0, const float* __restrict__ A1,
               const float* __restrict__ B0, const float* __restrict__ B1,
               float* __restrict__ C, float* __restrict__ BIN,
               u32 k3a0, u32 k3b0, u32 k3a1, u32 k3b1) {
  __shared__ float As[16][68], Bs[16][68];
  __shared__ float Ts[64][65];
  int tid = threadIdx.x;
  int tx = tid & 15, ty = tid >> 4;
  int rowBase = blockIdx.y * 64, colBase = blockIdx.x * 64;
  int br = blockIdx.z;
  const float* A = br ? A1 : A0;
  const float* Bm = br ? B1 : B0;
  u32 k3a = br ? k3a1 : k3a0, k3b = br ? k3b1 : k3b0;
  float* Cd = C + (size_t)br * BB * KK;
  float* Bd = BIN + (size_t)br * KK * BB;
  float c[4][4] = {};
  for (int kt = 0; kt < 256; kt += 16) {
#pragma unroll
    for (int q = 0; q < 4; q++) {
      int idx = tid + 256 * q;
      int kkx = idx & 15, rr = idx >> 4;
      As[kkx][rr] = A[(size_t)(rowBase + rr) * 256 + kt + kkx];
      Bs[kkx][rr] = Bm[(size_t)(colBase + rr) * 256 + kt + kkx];
    }
    __syncthreads();
#pragma unroll
    for (int kx = 0; kx < 16; kx++) {
      float4 a4 = *(const float4*)&As[kx][ty * 4];
      float4 b4 = *(const float4*)&Bs[kx][tx * 4];
      float av[4] = {a4.x, a4.y, a4.z, a4.w};
      float bv[4] = {b4.x, b4.y, b4.z, b4.w};
#pragma unroll
      for (int r = 0; r < 4; r++)
#pragma unroll
        for (int q = 0; q < 4; q++)
          c[r][q] = fmaf(av[r], bv[q], c[r][q]);
    }
    __syncthreads();
  }
#pragma unroll
  for (int r = 0; r < 4; r++)
#pragma unroll
    for (int q = 0; q < 4; q++) {
      Cd[(size_t)(rowBase + ty * 4 + r) * KK + colBase + tx * 4 + q] = c[r][q];
      Ts[ty * 4 + r][tx * 4 + q] = c[r][q];
    }
  __syncthreads();
#pragma unroll
  for (int p = 0; p < 16; p++) {
    int idx = p * 256 + tid;
    int kl = idx >> 6, bl = idx & 63;
    float x = Ts[bl][kl];
    float prob = 1.0f / (1.0f + expf(-x));
    int k = colBase + kl, b = rowBase + bl;
    u32 i = (u32)(k * BB + b);
    float eps = u01f(rbits32(k3a, k3b, i));
    Bd[(size_t)k * BB + b] = (prob > eps) ? 1.0f : 0.0f;
  }
}

// agg_n partials = Y @ ctx (NN), split-K S=2; grid (DD/64, BB/64, 4)
__global__ __launch_bounds__(256)
void k_gemm_aggn(const float* __restrict__ Yb, const float* __restrict__ B0,
                 const float* __restrict__ B1, float* __restrict__ CPN) {
  __shared__ float As[16][68], Bs[16][68];
  int tid = threadIdx.x;
  int tx = tid & 15, ty = tid >> 4;
  int rowBase = blockIdx.y * 64, colBase = blockIdx.x * 64;
  int br = blockIdx.z >> 1, s = blockIdx.z & 1;
  const float* A = Yb + (size_t)br * BB * KK;
  const float* Bm = br ? B1 : B0;
  int k0 = s * 256;
  float c[4][4] = {};
  for (int kt = k0; kt < k0 + 256; kt += 16) {
#pragma unroll
    for (int q = 0; q < 4; q++) {
      int idx = tid + 256 * q;
      int kkx = idx & 15, rr = idx >> 4;
      As[kkx][rr] = A[(size_t)(rowBase + rr) * KK + kt + kkx];
      int kk = (tid >> 6) * 4 + q;
      int jj = tid & 63;
      Bs[kk][jj] = Bm[(size_t)(kt + kk) * DD + colBase + jj];
    }
    __syncthreads();
#pragma unroll
    for (int kx = 0; kx < 16; kx++) {
      float4 a4 = *(const float4*)&As[kx][ty * 4];
      float4 b4 = *(const float4*)&Bs[kx][tx * 4];
      float av[4] = {a4.x, a4.y, a4.z, a4.w};
      float bv[4] = {b4.x, b4.y, b4.z, b4.w};
#pragma unroll
      for (int r = 0; r < 4; r++)
#pragma unroll
        for (int q = 0; q < 4; q++)
          c[r][q] = fmaf(av[r], bv[q], c[r][q]);
    }
    __syncthreads();
  }
  float* dst = CPN + (size_t)blockIdx.z * BB * DD;
#pragma unroll
  for (int r = 0; r < 4; r++)
#pragma unroll
    for (int q = 0; q < 4; q++)
      dst[(size_t)(rowBase + ty * 4 + r) * DD + colBase + tx * 4 + q] = c[r][q];
}

// agg_k partials = BIN @ feat (NN), split-K S=16; grid (DD/64, KK/64, 32)
__global__ __launch_bounds__(256)
void k_gemm_aggk(const float* __restrict__ BIN, const float* __restrict__ B0,
                 const float* __restrict__ B1, float* __restrict__ CP) {
  __shared__ float As[16][68], Bs[16][68];
  int tid = threadIdx.x;
  int tx = tid & 15, ty = tid >> 4;
  int rowBase = blockIdx.y * 64, colBase = blockIdx.x * 64;
  int br = blockIdx.z >> 4, s = blockIdx.z & 15;
  const float* A = BIN + (size_t)br * KK * BB;
  const float* Bm = br ? B1 : B0;
  int k0 = s * 256;
  float c[4][4] = {};
  for (int kt = k0; kt < k0 + 256; kt += 16) {
#pragma unroll
    for (int q = 0; q < 4; q++) {
      int idx = tid + 256 * q;
      int kkx = idx & 15, rr = idx >> 4;
      As[kkx][rr] = A[(size_t)(rowBase + rr) * BB + kt + kkx];
      int kk = (tid >> 6) * 4 + q;
      int jj = tid & 63;
      Bs[kk][jj] = Bm[(size_t)(kt + kk) * DD + colBase + jj];
    }
    __syncthreads();
#pragma unroll
    for (int kx = 0; kx < 16; kx++) {
      float4 a4 = *(const float4*)&As[kx][ty * 4];
      float4 b4 = *(const float4*)&Bs[kx][tx * 4];
      float av[4] = {a4.x, a4.y, a4.z, a4.w};
      float bv[4] = {b4.x, b4.y, b4.z, b4.w};
#pragma unroll
      for (int r = 0; r < 4; r++)
#pragma unroll
        for (int q = 0; q < 4; q++)
          c[r][q] = fmaf(av[r], bv[q], c[r][q]);
    }
    __syncthreads();
  }
  float* dst = CP + (size_t)blockIdx.z * KK * DD;
#pragma unroll
  for (int r = 0; r < 4; r++)
#pragma unroll
    for (int q = 0; q < 4; q++)
      dst[(size_t)(rowBase + ty * 4 + r) * DD + colBase + tx * 4 + q] = c[r][q];
}

// merged reduce: grid (4608, 2). x<4096: aggn S=2 sum; else aggk S=16 sum + div.
__global__ __launch_bounds__(256)
void k_reduce(const float* __restrict__ CPN, const float* __restrict__ CP,
              const float* __restrict__ rs2,
              float* __restrict__ N0, float* __restrict__ N1,
              float* __restrict__ K0, float* __restrict__ K1,
              float* __restrict__ sqpN, float* __restrict__ sqpK) {
  __shared__ float sq[256];
  int tid = threadIdx.x, br = blockIdx.y;
  float v;
  if (blockIdx.x < 4096) {
    int i = blockIdx.x * 256 + tid;
    const int MN = BB * DD;
    v = CPN[(size_t)(2 * br) * MN + i] + CPN[(size_t)(2 * br + 1) * MN + i];
    (br ? N1 : N0)[i] = v;
  } else {
    int i = (blockIdx.x - 4096) * 256 + tid;
    const int MN = KK * DD;
    const float* cp = CP + (size_t)br * 16 * MN;
    float s = 0.0f;
    for (int t = 0; t < 16; t++) s += cp[(size_t)t * MN + i];
    v = s / (rs2[br * KK + (i >> 8)] + 1e-8f);
    (br ? K1 : K0)[i] = v;
  }
  sq[tid] = v * v; __syncthreads();
  for (int off = 128; off > 0; off >>= 1) {
    if (tid < off) sq[tid] += sq[tid + off];
    __syncthreads();
  }
  if (tid == 0) {
    if (blockIdx.x < 4096) sqpN[br * 4096 + blockIdx.x] = sq[0];
    else sqpK[br * 512 + (blockIdx.x - 4096)] = sq[0];
  }
}

// merged scale: grid (1152, 2). x<1024: aggn; else aggk.
__global__ __launch_bounds__(256)
void k_scale(float* __restrict__ N0, float* __restrict__ N1,
             float* __restrict__ K0, float* __restrict__ K1,
             const float* __restrict__ sqpN, const float* __restrict__ sqpK) {
  __shared__ float sm[256];
  int tid = threadIdx.x, br = blockIdx.y;
  int isK = (blockIdx.x >= 1024);
  const float* sq = isK ? (sqpK + br * 512) : (sqpN + br * 4096);
  int np = isK ? 512 : 4096;
  float a = 0.0f;
  for (int i = tid; i < np; i += 256) a += sq[i];
  sm[tid] = a; __syncthreads();
  for (int off = 128; off > 0; off >>= 1) {
    if (tid < off) sm[tid] += sm[tid + off];
    __syncthreads();
  }
  float f = (float)(1.0 / sqrt((double)fmaxf(sm[0], 1e-12f)));
  float* data = isK ? (br ? K1 : K0) : (br ? N1 : N0);
  int xb = isK ? (blockIdx.x - 1024) : blockIdx.x;
  int i = (xb * 256 + tid) * 4;
  float4 v = *(const float4*)(data + i);
  v.x *= f; v.y *= f; v.z *= f; v.w *= f;
  *(float4*)(data + i) = v;
}

// ---------------- softmax(y1) + argmax(y2) with certainty-gap fast path ----------------
// Fast path: f32-log gumbels (same RNG bits), block top-2; commit if
// top1-top2 > 5e-5 (fast-gumbel abs err <= ~2e-6; exp/div monotonic ->
// argmax(y)=argmax(w)). Else fall back to the bit-exact f64 path (rare,
// block-uniform, deterministic).
__global__ __launch_bounds__(256)
void k_softmax_assign(const float* __restrict__ T, float* __restrict__ Y,
                      float* __restrict__ assignOut,
                      u32 g1a0, u32 g1b0, u32 g1a1, u32 g1b1, u32 g2a, u32 g2b) {
  __shared__ float smA[4], smS[4], smM2[4], smS2[4], smV[4], smV2[4];
  __shared__ int smI[4];
  int bid = blockIdx.x, tid = threadIdx.x;
  int br = bid >> 12, b = bid & 4095;
  u32 g1a = br ? g1a1 : g1a0, g1b = br ? g1b1 : g1b0;
  const float* knT = T + (size_t)br * BB * KK;
  float* Yd = Y + (size_t)br * BB * KK;
  int lane = tid & 63, wid = tid >> 6;
  int i0 = b * KK + tid, i1 = i0 + 256;
  float x0 = knT[i0], x1 = knT[i1];

  float z0 = x0 + gumbel_f32(g1a, g1b, (u32)i0);
  float z1 = x1 + gumbel_f32(g1a, g1b, (u32)i1);
  float wm = fmaxf(z0, z1);
#pragma unroll
  for (int off = 1; off < 64; off <<= 1) wm = fmaxf(wm, __shfl_xor(wm, off, 64));
  if (lane == 0) smA[wid] = wm;
  __syncthreads();
  float m = fmaxf(fmaxf(smA[0], smA[1]), fmaxf(smA[2], smA[3]));
  float e0 = expf(z0 - m), e1 = expf(z1 - m);
  float ws = e0 + e1;
#pragma unroll
  for (int off = 1; off < 64; off <<= 1) ws += __shfl_xor(ws, off, 64);
  if (lane == 0) smS[wid] = ws;
  __syncthreads();
  float s = (smS[0] + smS[1]) + (smS[2] + smS[3]);
  Yd[i0] = e0 / s;
  Yd[i1] = e1 / s;

  if (br == 0) {
    // ---- fast top-2 on f32-log gumbels ----
    float wf0 = x0 + gumbel_f32(g2a, g2b, (u32)i0);
    float wf1 = x1 + gumbel_f32(g2a, g2b, (u32)i1);
    float v1, v2; int i1x;
    if (wf0 >= wf1) { v1 = wf0; i1x = tid; v2 = wf1; }
    else            { v1 = wf1; i1x = tid + 256; v2 = wf0; }
#pragma unroll
    for (int off = 1; off < 64; off <<= 1) {
      float ov1 = __shfl_xor(v1, off, 64);
      int   oi1 = __shfl_xor(i1x, off, 64);
      float ov2 = __shfl_xor(v2, off, 64);
      float n1; int ni;
      if (ov1 > v1 || (ov1 == v1 && oi1 < i1x)) { n1 = ov1; ni = oi1; v2 = fmaxf(v1, ov2); }
      else { n1 = v1; ni = i1x; v2 = fmaxf(v2, ov1 == v1 ? ov2 : ov1); }
      // note: when ov1==v1 (same value), the loser v1 still counts toward v2
      if (ov1 == v1 && oi1 != i1x) v2 = fmaxf(v2, ov1);
      v1 = n1; i1x = ni;
    }
    if (lane == 0) { smV[wid] = v1; smI[wid] = i1x; smV2[wid] = v2; }
    __syncthreads();
    __shared__ int needSlow;
    if (tid == 0) {
      float cv = smV[0]; int ci = smI[0]; float c2 = smV2[0];
#pragma unroll
      for (int t = 1; t < 4; t++) {
        float tv = smV[t]; int ti = smI[t]; float t2 = smV2[t];
        if (tv > cv || (tv == cv && ti < ci)) { c2 = fmaxf(cv, t2); cv = tv; ci = ti; }
        else c2 = fmaxf(c2, tv);
      }
      if (cv - c2 > 5e-5f) { assignOut[b] = (float)ci; needSlow = 0; }
      else needSlow = 1;
    }
    __syncthreads();
    if (needSlow) {
      // ---- exact f64-log path (bit-identical to prior rounds) ----
      float w0 = x0 + gumbel_at(g2a, g2b, (u32)i0);
      float w1 = x1 + gumbel_at(g2a, g2b, (u32)i1);
      float wm2 = fmaxf(w0, w1);
#pragma unroll
      for (int off = 1; off < 64; off <<= 1) wm2 = fmaxf(wm2, __shfl_xor(wm2, off, 64));
      if (lane == 0) smM2[wid] = wm2;
      __syncthreads();
      float m2 = fmaxf(fmaxf(smM2[0], smM2[1]), fmaxf(smM2[2], smM2[3]));
      float f0 = expf(w0 - m2), f1 = expf(w1 - m2);
      float ws2 = f0 + f1;
#pragma unroll
      for (int off = 1; off < 64; off <<= 1) ws2 += __shfl_xor(ws2, off, 64);
      if (lane == 0) smS2[wid] = ws2;
      __syncthreads();
      float s2 = (smS2[0] + smS2[1]) + (smS2[2] + smS2[3]);
      float y0 = f0 / s2, y1v = f1 / s2;
      float bv; int bi;
      if (y1v > y0) { bv = y1v; bi = tid + 256; } else { bv = y0; bi = tid; }
#pragma unroll
      for (int off = 1; off < 64; off <<= 1) {
        float ov = __shfl_xor(bv, off, 64);
        int oi = __shfl_xor(bi, off, 64);
        if (ov > bv || (ov == bv && oi < bi)) { bv = ov; bi = oi; }
      }
      if (lane == 0) { smV[wid] = bv; smI[wid] = bi; }
      __syncthreads();
      if (tid == 0) {
        float cv = smV[0]; int ci = smI[0];
#pragma unroll
        for (int t = 1; t < 4; t++) {
          if (smV[t] > cv || (smV[t] == cv && smI[t] < ci)) { cv = smV[t]; ci = smI[t]; }
        }
        assignOut[b] = (float)ci;
      }
    }
  }
}

// ---------------- row sums of BIN ----------------
__global__ __launch_bounds__(256)
void k_rowsum(const float* __restrict__ BIN, float* __restrict__ rs2) {
  __shared__ float sm[4];
  int row = blockIdx.x;
  const float* src = BIN + (size_t)row * BB;
  int tid = threadIdx.x, l = tid & 63, w = tid >> 6;
  float s = 0.0f;
#pragma unroll
  for (int p = 0; p < 4; p++) {
    float4 v = *(const float4*)(src + (p * 256 + tid) * 4);
    s += (v.x + v.y) + (v.z + v.w);
  }
#pragma unroll
  for (int off = 1; off < 64; off <<= 1) s += __shfl_xor(s, off, 64);
  if (l == 0) sm[w] = s;
  __syncthreads();
  if (tid == 0) rs2[row] = (sm[0] + sm[1]) + (sm[2] + sm[3]);
}

// ---------------- Taylor-collapsed InfoNCE loss, batched (1152 blocks) ----------------
__global__ __launch_bounds__(256)
void k_loss_row(const float* __restrict__ QN, const float* __restrict__ KPN,
                const float* __restrict__ QK, const float* __restrict__ KPK,
                const float* __restrict__ csum, const float* __restrict__ lscp,
                float* __restrict__ LPN, float* __restrict__ LPK) {
  __shared__ float pt[4];
  int w = threadIdx.x >> 6, l = threadIdx.x & 63;
  int bid = blockIdx.x;
  int isK = (bid >= 1024);
  int rb = isK ? (bid - 1024) : bid;
  const float* Q  = isK ? QK : QN;
  const float* KP = isK ? KPK : KPN;
  const float* cs4 = csum + (isK ? 256 : 0);
  float Lc = isK ? (float)QQ : (float)LL;
  float lsc = lscp[isK ? 1 : 0];
  int r = rb * 4 + w;
  float4 q = *(const float4*)(Q + (size_t)r * 256 + l * 4);
  float4 kp = *(const float4*)(KP + (size_t)r * 256 + l * 4);
  float4 cs = *(const float4*)(cs4 + l * 4);
  float d1 = q.x * kp.x + q.y * kp.y + q.z * kp.z + q.w * kp.w;
  float d2 = q.x * cs.x + q.y * cs.y + q.z * cs.z + q.w * cs.w;
#pragma unroll
  for (int off = 1; off < 64; off <<= 1) {
    d1 += __shfl_xor(d1, off, 64);
    d2 += __shfl_xor(d2, off, 64);
  }
  if (l == 0) {
    float z0 = d1 / 0.07f;
    double S = (double)Lc + (double)expf(z0) + (double)(lsc * d2);
    pt[w] = (float)(log(S)) - z0;
  }
  __syncthreads();
  if (threadIdx.x == 0) {
    float v = (pt[0] + pt[1]) + (pt[2] + pt[3]);
    if (isK) LPK[rb] = v; else LPN[rb] = v;
  }
}

__global__ __launch_bounds__(256)
void k_loss_final(const float* __restrict__ LPN, int nN, float invMN,
                  const float* __restrict__ LPK, int nK, float invMK,
                  float* __restrict__ outLoss) {
  __shared__ float sm[256];
  int tid = threadIdx.x;
  float a = 0.0f;
  for (int i = tid; i < nN; i += 256) a += LPN[i];
  sm[tid] = a; __syncthreads();
  for (int off = 128; off > 0; off >>= 1) {
    if (tid < off) sm[tid] += sm[tid + off];
    __syncthreads();
  }
  float lossN = sm[0] * invMN;
  __syncthreads();
  float b = 0.0f;
  for (int i = tid; i < nK; i += 256) b += LPK[i];
  sm[tid] = b; __syncthreads();
  for (int off = 128; off > 0; off >>= 1) {
    if (tid < off) sm[tid] += sm[tid + off];
    __syncthreads();
  }
  if (tid == 0) outLoss[0] = lossN + sm[0] * invMK;
}

// ---------------- launch ----------------
extern "C" void kernel_launch(void* const* d_in, const int* in_sizes, int n_in,
                              void* d_out, int out_size, void* d_ws, size_t ws_size,
                              hipStream_t stream) {
  const float* feat0 = (const float*)d_in[0];
  const float* feat1 = (const float*)d_in[1];
  const float* ctx0  = (const float*)d_in[2];
  const float* ctx1  = (const float*)d_in[3];
  const float* queue_n = (const float*)d_in[4];
  const float* queue_k = (const float*)d_in[5];

  float* W = (float*)d_ws;
  size_t o = 0;
  float* T     = W + o; o += 2 * (size_t)BB * KK;
  float* Yb    = W + o; o += 2 * (size_t)BB * KK;
  float* BIN   = W + o; o += 2 * (size_t)KK * BB;
  float* CP    = W + o; o += 32 * (size_t)KK * DD;
  float* CPN   = W + o; o += 4 * (size_t)BB * DD;
  float* AGGN1 = W + o; o += (size_t)BB * DD;
  float* AGGK1 = W + o; o += (size_t)KK * DD;
  float* RS2   = W + o; o += 2 * KK;
  float* CPS   = W + o; o += 2 * 131072;
  float* SQ2   = W + o; o += 2 * 512;
  float* CS    = W + o; o += 2 * 256;
  float* LSC   = W + o; o += 2;
  float* LPN   = W + o; o += 1024;
  float* LPK   = W + o; o += 128;
  float* PART_K = W + o; o += 256;
  float* SQPN  = W + o; o += 2 * 4096;
  float* SQPK  = W + o; o += 2 * 512;

  float* out = (float*)d_out;
  float* outAssign = out;
  float* outAggn2  = out + BB;
  float* outAggk2  = out + BB + (size_t)BB * DD;
  float* outLoss   = out + BB + (size_t)BB * DD + (size_t)KK * DD;

  u32 kq0, kq1, kc[2][2];
  tf2x32(0u, 42u, 0u, 0u, kq0, kq1);
  tf2x32(0u, 42u, 0u, 1u, kc[0][0], kc[0][1]);
  tf2x32(0u, 42u, 0u, 2u, kc[1][0], kc[1][1]);
  u32 sub[2][3][2];
  for (int br = 0; br < 2; br++)
    for (int t = 0; t < 3; t++)
      tf2x32(kc[br][0], kc[br][1], 0u, (u32)t, sub[br][t][0], sub[br][t][1]);

  // stats chain
  k_sumsq<<<256, 256, 0, stream>>>(queue_k, QQ * DD, PART_K);
  k_stats<<<dim3(512, 2), 256, 0, stream>>>(queue_n, queue_k, PART_K, CPS, SQ2, kq0, kq1);
  k_finalize<<<dim3(257, 2), 256, 0, stream>>>(CPS, SQ2, CS, LSC);

  // batched branch pipeline
  k_gemm_nt<<<dim3(KK / 64, BB / 64, 2), 256, 0, stream>>>(
      feat0, feat1, ctx0, ctx1, T, BIN,
      sub[0][2][0], sub[0][2][1], sub[1][2][0], sub[1][2][1]);
  k_softmax_assign<<<2 * BB, 256, 0, stream>>>(T, Yb, outAssign,
      sub[0][0][0], sub[0][0][1], sub[1][0][0], sub[1][0][1], sub[0][1][0], sub[0][1][1]);
  k_rowsum<<<2 * KK, 256, 0, stream>>>(BIN, RS2);
  k_gemm_aggn<<<dim3(DD / 64, BB / 64, 4), 256, 0, stream>>>(Yb, ctx0, ctx1, CPN);
  k_gemm_aggk<<<dim3(DD / 64, KK / 64, 32), 256, 0, stream>>>(BIN, feat0, feat1, CP);
  k_reduce<<<dim3(4608, 2), 256, 0, stream>>>(CPN, CP, RS2, AGGN1, outAggn2,
                                              AGGK1, outAggk2, SQPN, SQPK);
  k_scale<<<dim3(1152, 2), 256, 0, stream>>>(AGGN1, outAggn2, AGGK1, outAggk2, SQPN, SQPK);

  // Taylor-collapsed losses
  k_loss_row<<<1152, 256, 0, stream>>>(AGGN1, outAggn2, AGGK1, outAggk2, CS, LSC, LPN, LPK);
  k_loss_final<<<1, 256, 0, stream>>>(LPN, BB / 4, 1.0f / BB, LPK, KK / 4, 1.0f / KK, outLoss);
}

// Round 19
// 176.263 us; speedup vs baseline: 1.6390x; 1.1810x over previous
//
#include <hip/hip_runtime.h>
#include <stdint.h>
#include <math.h>

typedef unsigned int u32;
typedef unsigned short u16;
typedef __attribute__((ext_vector_type(8))) short short8;
typedef __attribute__((ext_vector_type(4))) float f32x4;

#define BB 4096
#define DD 256
#define KK 512
#define LL 32768
#define QQ 8192

// ---------------- Threefry2x32 (JAX-exact, 20 rounds) ----------------
__host__ __device__ inline void tf2x32(u32 k0, u32 k1, u32 c0, u32 c1, u32& o0, u32& o1) {
  u32 ks2 = k0 ^ k1 ^ 0x1BD11BDAu;
  u32 x0 = c0 + k0, x1 = c1 + k1;
#define TF_R(r) { x0 += x1; x1 = ((x1 << (r)) | (x1 >> (32 - (r)))); x1 ^= x0; }
  TF_R(13) TF_R(15) TF_R(26) TF_R(6)
  x0 += k1; x1 += ks2 + 1u;
  TF_R(17) TF_R(29) TF_R(16) TF_R(24)
  x0 += ks2; x1 += k0 + 2u;
  TF_R(13) TF_R(15) TF_R(26) TF_R(6)
  x0 += k0; x1 += k1 + 3u;
  TF_R(17) TF_R(29) TF_R(16) TF_R(24)
  x0 += k1; x1 += ks2 + 4u;
  TF_R(13) TF_R(15) TF_R(26) TF_R(6)
  x0 += ks2; x1 += k0 + 5u;
#undef TF_R
  o0 = x0; o1 = x1;
}

__device__ inline u32 rbits32(u32 k0, u32 k1, u32 i) {
  u32 a, b;
  tf2x32(k0, k1, 0u, i, a, b);
  return a ^ b;
}

__device__ inline float u01f(u32 bits) {
  return __uint_as_float(0x3f800000u | (bits >> 9)) - 1.0f;
}

// f64-log gumbel: argmax fallback path (bit-stable vs CPU libm)
__device__ inline float gumbel_at(u32 k0, u32 k1, u32 i) {
  float f = u01f(rbits32(k0, k1, i));
  float u = fmaxf(1e-20f, f + 1e-20f);
  float l1 = (float)log((double)u);
  float l2 = (float)log((double)(-l1));
  return -l2;
}

// fast f32 gumbel
__device__ inline float gumbel_f32(u32 k0, u32 k1, u32 i) {
  float f = u01f(rbits32(k0, k1, i));
  float u = fmaxf(1e-20f, f + 1e-20f);
  float l1 = __logf(u);
  return -__logf(-l1);
}

// XLA f32 ErfInv (Giles polynomial)
__device__ inline float erfinv32(float x) {
  float w = -log1pf(-x * x);
  float p;
  if (w < 5.0f) {
    w -= 2.5f;
    p = 2.81022636e-08f;
    p = fmaf(p, w, 3.43273939e-07f);
    p = fmaf(p, w, -3.5233877e-06f);
    p = fmaf(p, w, -4.39150654e-06f);
    p = fmaf(p, w, 0.00021858087f);
    p = fmaf(p, w, -0.00125372503f);
    p = fmaf(p, w, -0.00417768164f);
    p = fmaf(p, w, 0.246640727f);
    p = fmaf(p, w, 1.50140941f);
  } else {
    w = sqrtf(w) - 3.0f;
    p = -0.000200214257f;
    p = fmaf(p, w, 0.000100950558f);
    p = fmaf(p, w, 0.00134934322f);
    p = fmaf(p, w, -0.00367342844f);
    p = fmaf(p, w, 0.00573950773f);
    p = fmaf(p, w, -0.0076224613f);
    p = fmaf(p, w, 0.00943887047f);
    p = fmaf(p, w, 1.00167406f);
    p = fmaf(p, w, 2.83297682f);
  }
  return p * x;
}

__device__ inline u16 f2bf(float f) {
  u32 u = __float_as_uint(f);
  u32 r = (u + 0x7FFFu + ((u >> 16) & 1u)) >> 16;
  return (u16)r;
}

// ---------------- queue_k raw sumsq (for sk) ----------------
__global__ __launch_bounds__(256)
void k_sumsq(const float* __restrict__ x, int n, float* __restrict__ partial) {
  __shared__ float sm[256];
  float s = 0.0f;
  for (int i = blockIdx.x * 256 + threadIdx.x; i < n; i += gridDim.x * 256) {
    float v = x[i]; s = fmaf(v, v, s);
  }
  sm[threadIdx.x] = s; __syncthreads();
  for (int off = 128; off > 0; off >>= 1) {
    if (threadIdx.x < off) sm[threadIdx.x] += sm[threadIdx.x + off];
    __syncthreads();
  }
  if (threadIdx.x == 0) partial[blockIdx.x] = sm[0];
}

// ---------------- fused stats: z=0 queue_n, z=1 constructed queue ----------------
__global__ __launch_bounds__(256)
void k_stats(const float* __restrict__ qn, const float* __restrict__ qk_in,
             const float* __restrict__ partK,
             float* __restrict__ colpart, float* __restrict__ sqpart,
             u32 kqa, u32 kqb) {
  __shared__ float smc[4][256];
  __shared__ float sm[256];
  int tid = threadIdx.x, g = tid >> 6, l = tid & 63;
  int z = blockIdx.y;
  float4 ca = {0.f, 0.f, 0.f, 0.f};
  float ss = 0.0f;
  if (z == 0) {
    int base = blockIdx.x * 64;
    for (int j = base + g; j < base + 64; j += 4) {
      float4 v = *(const float4*)(qn + (size_t)j * 256 + l * 4);
      ca.x += v.x; ca.y += v.y; ca.z += v.z; ca.w += v.w;
      ss = fmaf(v.x, v.x, ss); ss = fmaf(v.y, v.y, ss);
      ss = fmaf(v.z, v.z, ss); ss = fmaf(v.w, v.w, ss);
    }
  } else {
    sm[tid] = partK[tid]; __syncthreads();
    for (int off = 128; off > 0; off >>= 1) {
      if (tid < off) sm[tid] += sm[tid + off];
      __syncthreads();
    }
    float sk = (float)(1.0 / sqrt((double)fmaxf(sm[0], 1e-12f)));
    __syncthreads();
    const float lo = -0.99999994f;
    int base = blockIdx.x * 16;
    for (int j = base + g; j < base + 16; j += 4) {
      int i0 = j * 256 + l * 4;
      float4 v = *(const float4*)(qk_in + i0);
      float vin[4] = {v.x, v.y, v.z, v.w};
      float valv[4];
#pragma unroll
      for (int e = 0; e < 4; e++) {
        float qk = vin[e] * sk;
        float f = u01f(rbits32(kqa, kqb, (u32)(i0 + e)));
        float u = fmaxf(lo, f * 2.0f + lo);
        float nv = 1.41421354f * erfinv32(u);
        float t = qk + 0.1f * nv;
        valv[e] = t + qk;
        ss = fmaf(valv[e], valv[e], ss);
      }
      ca.x += valv[0]; ca.y += valv[1]; ca.z += valv[2]; ca.w += valv[3];
    }
  }
  smc[g][l * 4 + 0] = ca.x; smc[g][l * 4 + 1] = ca.y;
  smc[g][l * 4 + 2] = ca.z; smc[g][l * 4 + 3] = ca.w;
  sm[tid] = ss; __syncthreads();
  colpart[(size_t)z * 131072 + blockIdx.x * 256 + tid] =
      (smc[0][tid] + smc[1][tid]) + (smc[2][tid] + smc[3][tid]);
  for (int off = 128; off > 0; off >>= 1) {
    if (tid < off) sm[tid] += sm[tid + off];
    __syncthreads();
  }
  if (tid == 0) sqpart[z * 512 + blockIdx.x] = sm[0];
}

// merged finalize: grid (257, 2)
__global__ __launch_bounds__(256)
void k_finalize(const float* __restrict__ colpart, const float* __restrict__ sqpart,
                float* __restrict__ csum, float* __restrict__ lscOut) {
  __shared__ float sm[256];
  int z = blockIdx.y, t = threadIdx.x;
  if (blockIdx.x < 256) {
    int d = blockIdx.x;
    const float* cp = colpart + (size_t)z * 131072;
    float a = cp[(size_t)t * 256 + d] + cp[(size_t)(t + 256) * 256 + d];
    sm[t] = a; __syncthreads();
    for (int off = 128; off > 0; off >>= 1) {
      if (t < off) sm[t] += sm[t + off];
      __syncthreads();
    }
    if (t == 0) csum[z * 256 + d] = sm[0];
  } else {
    const float* sq = sqpart + z * 512;
    float a = sq[t] + sq[t + 256];
    sm[t] = a; __syncthreads();
    for (int off = 128; off > 0; off >>= 1) {
      if (t < off) sm[t] += sm[t + off];
      __syncthreads();
    }
    if (t == 0) {
      float sr = (float)(1.0 / sqrt((double)fmaxf(sm[0], 1e-12f)));
      lscOut[z] = sr / 0.07f;
    }
  }
}

// ---------------- pack feat/ctx into MFMA B-fragment bf16 layout ----------------
// featP[br][d>>4][b>>5][lane][e]: lane=(d&15)|(((b>>3)&3)<<4), e=b&7
// ctxP [br][n>>4][k>>5][lane][e]: lane=(n&15)|(((k>>3)&3)<<4), e=k&7
__global__ __launch_bounds__(256)
void k_pack(const float* __restrict__ f0, const float* __restrict__ f1,
            const float* __restrict__ c0, const float* __restrict__ c1,
            u16* __restrict__ featP, u16* __restrict__ ctxP) {
  int idx = blockIdx.x * 256 + threadIdx.x;
  if (idx < 2 * BB * DD) {
    int br = idx >> 20;
    int r = idx & ((1 << 20) - 1);
    int b = r >> 8, d = r & 255;
    float v = (br ? f1 : f0)[r];
    size_t dst = ((size_t)(br * 16 + (d >> 4)) * 128 + (b >> 5)) * 512 +
                 (((d & 15) | (((b >> 3) & 3) << 4)) * 8) + (b & 7);
    featP[dst] = f2bf(v);
  } else {
    int j = idx - 2 * BB * DD;
    if (j < 2 * KK * DD) {
      int br = j >> 17;
      int r = j & 131071;
      int k = r >> 8, n = r & 255;
      float v = (br ? c1 : c0)[r];
      size_t dst = ((size_t)(br * 16 + (n >> 4)) * 16 + (k >> 5)) * 512 +
                   (((n & 15) | (((k >> 3) & 3) << 4)) * 8) + (k & 7);
      ctxP[dst] = f2bf(v);
    }
  }
}

// ---------------- knT GEMM (64x64, 4x4) + fused binary (packed bf16 out) ----------------
__global__ __launch_bounds__(256)
void k_gemm_nt(const float* __restrict__ A0, const float* __restrict__ A1,
               const float* __restrict__ B0, const float* __restrict__ B1,
               float* __restrict__ C, u16* __restrict__ BINP,
               u32 k3a0, u32 k3b0, u32 k3a1, u32 k3b1) {
  __shared__ float As[16][68], Bs[16][68];
  __shared__ float Ts[64][65];
  int tid = threadIdx.x;
  int tx = tid & 15, ty = tid >> 4;
  int rowBase = blockIdx.y * 64, colBase = blockIdx.x * 64;
  int br = blockIdx.z;
  const float* A = br ? A1 : A0;
  const float* Bm = br ? B1 : B0;
  u32 k3a = br ? k3a1 : k3a0, k3b = br ? k3b1 : k3b0;
  float* Cd = C + (size_t)br * BB * KK;
  u16* Bd = BINP + (size_t)br * 32 * 128 * 512;
  float c[4][4] = {};
  for (int kt = 0; kt < 256; kt += 16) {
#pragma unroll
    for (int q = 0; q < 4; q++) {
      int idx = tid + 256 * q;
      int kkx = idx & 15, rr = idx >> 4;
      As[kkx][rr] = A[(size_t)(rowBase + rr) * 256 + kt + kkx];
      Bs[kkx][rr] = Bm[(size_t)(colBase + rr) * 256 + kt + kkx];
    }
    __syncthreads();
#pragma unroll
    for (int kx = 0; kx < 16; kx++) {
      float4 a4 = *(const float4*)&As[kx][ty * 4];
      float4 b4 = *(const float4*)&Bs[kx][tx * 4];
      float av[4] = {a4.x, a4.y, a4.z, a4.w};
      float bv[4] = {b4.x, b4.y, b4.z, b4.w};
#pragma unroll
      for (int r = 0; r < 4; r++)
#pragma unroll
        for (int q = 0; q < 4; q++)
          c[r][q] = fmaf(av[r], bv[q], c[r][q]);
    }
    __syncthreads();
  }
#pragma unroll
  for (int r = 0; r < 4; r++)
#pragma unroll
    for (int q = 0; q < 4; q++) {
      Cd[(size_t)(rowBase + ty * 4 + r) * KK + colBase + tx * 4 + q] = c[r][q];
      Ts[ty * 4 + r][tx * 4 + q] = c[r][q];
    }
  __syncthreads();
#pragma unroll
  for (int p = 0; p < 16; p++) {
    int idx = p * 256 + tid;
    int kl = idx >> 6, bl = idx & 63;
    float x = Ts[bl][kl];
    float prob = 1.0f / (1.0f + expf(-x));
    int k = colBase + kl, b = rowBase + bl;
    u32 i = (u32)(k * BB + b);
    float eps = u01f(rbits32(k3a, k3b, i));
    size_t bo = ((size_t)(k >> 4) * 128 + (b >> 5)) * 512 +
                (((k & 15) | (((b >> 3) & 3) << 4)) * 8) + (b & 7);
    Bd[bo] = (prob > eps) ? (u16)0x3F80 : (u16)0;
  }
}

// ---------------- MFMA agg_n: CPN[br*2+s] = Y@ctx partial; grid (256, 2, 2) ----------------
__global__ __launch_bounds__(256)
void k_mfma_aggn(const u16* __restrict__ YP, const u16* __restrict__ ctxP,
                 float* __restrict__ CPN) {
  int gx = blockIdx.x, s = blockIdx.y, br = blockIdx.z;
  int tid = threadIdx.x, w = tid >> 6, lane = tid & 63;
  f32x4 acc0 = {0,0,0,0}, acc1 = {0,0,0,0}, acc2 = {0,0,0,0}, acc3 = {0,0,0,0};
  const u16* Ab = YP + ((size_t)(br * 256 + gx) * 16) * 512 + lane * 8;
  const u16* Bb = ctxP + ((size_t)(br * 16) * 16) * 512 + lane * 8;
  for (int kc = 0; kc < 8; kc++) {
    int kcg = s * 8 + kc;
    short8 a = *(const short8*)(Ab + (size_t)kcg * 512);
    short8 b0 = *(const short8*)(Bb + ((size_t)(w * 4 + 0) * 16 + kcg) * 512);
    short8 b1 = *(const short8*)(Bb + ((size_t)(w * 4 + 1) * 16 + kcg) * 512);
    short8 b2 = *(const short8*)(Bb + ((size_t)(w * 4 + 2) * 16 + kcg) * 512);
    short8 b3 = *(const short8*)(Bb + ((size_t)(w * 4 + 3) * 16 + kcg) * 512);
    acc0 = __builtin_amdgcn_mfma_f32_16x16x32_bf16(a, b0, acc0, 0, 0, 0);
    acc1 = __builtin_amdgcn_mfma_f32_16x16x32_bf16(a, b1, acc1, 0, 0, 0);
    acc2 = __builtin_amdgcn_mfma_f32_16x16x32_bf16(a, b2, acc2, 0, 0, 0);
    acc3 = __builtin_amdgcn_mfma_f32_16x16x32_bf16(a, b3, acc3, 0, 0, 0);
  }
  float* dst = CPN + (size_t)(br * 2 + s) * BB * DD;
  int rbase = gx * 16 + (lane >> 4) * 4;
  int cl = lane & 15;
#pragma unroll
  for (int r = 0; r < 4; r++) {
    dst[(size_t)(rbase + r) * 256 + (w * 4 + 0) * 16 + cl] = acc0[r];
    dst[(size_t)(rbase + r) * 256 + (w * 4 + 1) * 16 + cl] = acc1[r];
    dst[(size_t)(rbase + r) * 256 + (w * 4 + 2) * 16 + cl] = acc2[r];
    dst[(size_t)(rbase + r) * 256 + (w * 4 + 3) * 16 + cl] = acc3[r];
  }
}

// ---------------- MFMA agg_k: CP[br*16+s] = BIN@feat partial; grid (32, 16, 2) ----------------
__global__ __launch_bounds__(256)
void k_mfma_aggk(const u16* __restrict__ BINP, const u16* __restrict__ featP,
                 float* __restrict__ CP) {
  int gx = blockIdx.x, s = blockIdx.y, br = blockIdx.z;
  int tid = threadIdx.x, w = tid >> 6, lane = tid & 63;
  f32x4 acc0 = {0,0,0,0}, acc1 = {0,0,0,0}, acc2 = {0,0,0,0}, acc3 = {0,0,0,0};
  const u16* Ab = BINP + ((size_t)(br * 32 + gx) * 128) * 512 + lane * 8;
  const u16* Bb = featP + ((size_t)(br * 16) * 128) * 512 + lane * 8;
  for (int kc = 0; kc < 8; kc++) {
    int bcg = s * 8 + kc;
    short8 a = *(const short8*)(Ab + (size_t)bcg * 512);
    short8 b0 = *(const short8*)(Bb + ((size_t)(w * 4 + 0) * 128 + bcg) * 512);
    short8 b1 = *(const short8*)(Bb + ((size_t)(w * 4 + 1) * 128 + bcg) * 512);
    short8 b2 = *(const short8*)(Bb + ((size_t)(w * 4 + 2) * 128 + bcg) * 512);
    short8 b3 = *(const short8*)(Bb + ((size_t)(w * 4 + 3) * 128 + bcg) * 512);
    acc0 = __builtin_amdgcn_mfma_f32_16x16x32_bf16(a, b0, acc0, 0, 0, 0);
    acc1 = __builtin_amdgcn_mfma_f32_16x16x32_bf16(a, b1, acc1, 0, 0, 0);
    acc2 = __builtin_amdgcn_mfma_f32_16x16x32_bf16(a, b2, acc2, 0, 0, 0);
    acc3 = __builtin_amdgcn_mfma_f32_16x16x32_bf16(a, b3, acc3, 0, 0, 0);
  }
  float* dst = CP + (size_t)(br * 16 + s) * KK * DD;
  int rbase = gx * 16 + (lane >> 4) * 4;
  int cl = lane & 15;
#pragma unroll
  for (int r = 0; r < 4; r++) {
    dst[(size_t)(rbase + r) * 256 + (w * 4 + 0) * 16 + cl] = acc0[r];
    dst[(size_t)(rbase + r) * 256 + (w * 4 + 1) * 16 + cl] = acc1[r];
    dst[(size_t)(rbase + r) * 256 + (w * 4 + 2) * 16 + cl] = acc2[r];
    dst[(size_t)(rbase + r) * 256 + (w * 4 + 3) * 16 + cl] = acc3[r];
  }
}

// merged reduce: grid (4608, 2). x<4096: aggn S=2 sum; else aggk S=16 sum + div.
__global__ __launch_bounds__(256)
void k_reduce(const float* __restrict__ CPN, const float* __restrict__ CP,
              const float* __restrict__ rs2,
              float* __restrict__ N0, float* __restrict__ N1,
              float* __restrict__ K0, float* __restrict__ K1,
              float* __restrict__ sqpN, float* __restrict__ sqpK) {
  __shared__ float sq[256];
  int tid = threadIdx.x, br = blockIdx.y;
  float v;
  if (blockIdx.x < 4096) {
    int i = blockIdx.x * 256 + tid;
    const int MN = BB * DD;
    v = CPN[(size_t)(2 * br) * MN + i] + CPN[(size_t)(2 * br + 1) * MN + i];
    (br ? N1 : N0)[i] = v;
  } else {
    int i = (blockIdx.x - 4096) * 256 + tid;
    const int MN = KK * DD;
    const float* cp = CP + (size_t)br * 16 * MN;
    float s = 0.0f;
    for (int t = 0; t < 16; t++) s += cp[(size_t)t * MN + i];
    v = s / (rs2[br * KK + (i >> 8)] + 1e-8f);
    (br ? K1 : K0)[i] = v;
  }
  sq[tid] = v * v; __syncthreads();
  for (int off = 128; off > 0; off >>= 1) {
    if (tid < off) sq[tid] += sq[tid + off];
    __syncthreads();
  }
  if (tid == 0) {
    if (blockIdx.x < 4096) sqpN[br * 4096 + blockIdx.x] = sq[0];
    else sqpK[br * 512 + (blockIdx.x - 4096)] = sq[0];
  }
}

// merged scale: grid (1152, 2). x<1024: aggn; else aggk.
__global__ __launch_bounds__(256)
void k_scale(float* __restrict__ N0, float* __restrict__ N1,
             float* __restrict__ K0, float* __restrict__ K1,
             const float* __restrict__ sqpN, const float* __restrict__ sqpK) {
  __shared__ float sm[256];
  int tid = threadIdx.x, br = blockIdx.y;
  int isK = (blockIdx.x >= 1024);
  const float* sq = isK ? (sqpK + br * 512) : (sqpN + br * 4096);
  int np = isK ? 512 : 4096;
  float a = 0.0f;
  for (int i = tid; i < np; i += 256) a += sq[i];
  sm[tid] = a; __syncthreads();
  for (int off = 128; off > 0; off >>= 1) {
    if (tid < off) sm[tid] += sm[tid + off];
    __syncthreads();
  }
  float f = (float)(1.0 / sqrt((double)fmaxf(sm[0], 1e-12f)));
  float* data = isK ? (br ? K1 : K0) : (br ? N1 : N0);
  int xb = isK ? (blockIdx.x - 1024) : blockIdx.x;
  int i = (xb * 256 + tid) * 4;
  float4 v = *(const float4*)(data + i);
  v.x *= f; v.y *= f; v.z *= f; v.w *= f;
  *(float4*)(data + i) = v;
}

// ---------------- softmax(y1, packed bf16 out) + argmax fast path ----------------
__global__ __launch_bounds__(256)
void k_softmax_assign(const float* __restrict__ T, u16* __restrict__ YP,
                      float* __restrict__ assignOut,
                      u32 g1a0, u32 g1b0, u32 g1a1, u32 g1b1, u32 g2a, u32 g2b) {
  __shared__ float smA[4], smS[4], smM2[4], smS2[4], smV[4], smV2[4];
  __shared__ int smI[4];
  int bid = blockIdx.x, tid = threadIdx.x;
  int br = bid >> 12, b = bid & 4095;
  u32 g1a = br ? g1a1 : g1a0, g1b = br ? g1b1 : g1b0;
  const float* knT = T + (size_t)br * BB * KK;
  int lane = tid & 63, wid = tid >> 6;
  int i0 = b * KK + tid, i1 = i0 + 256;
  float x0 = knT[i0], x1 = knT[i1];

  float z0 = x0 + gumbel_f32(g1a, g1b, (u32)i0);
  float z1 = x1 + gumbel_f32(g1a, g1b, (u32)i1);
  float wm = fmaxf(z0, z1);
#pragma unroll
  for (int off = 1; off < 64; off <<= 1) wm = fmaxf(wm, __shfl_xor(wm, off, 64));
  if (lane == 0) smA[wid] = wm;
  __syncthreads();
  float m = fmaxf(fmaxf(smA[0], smA[1]), fmaxf(smA[2], smA[3]));
  float e0 = expf(z0 - m), e1 = expf(z1 - m);
  float ws = e0 + e1;
#pragma unroll
  for (int off = 1; off < 64; off <<= 1) ws += __shfl_xor(ws, off, 64);
  if (lane == 0) smS[wid] = ws;
  __syncthreads();
  float s = (smS[0] + smS[1]) + (smS[2] + smS[3]);
  // packed A-fragment bf16 writes: YP[br][b>>4][k>>5][lane][e]
  {
    int k0 = tid, k1 = tid + 256;
    size_t y0o = ((size_t)(br * 256 + (b >> 4)) * 16 + (k0 >> 5)) * 512 +
                 ((b & 15) | (((k0 >> 3) & 3) << 4)) * 8 + (k0 & 7);
    size_t y1o = ((size_t)(br * 256 + (b >> 4)) * 16 + (k1 >> 5)) * 512 +
                 ((b & 15) | (((k1 >> 3) & 3) << 4)) * 8 + (k1 & 7);
    YP[y0o] = f2bf(e0 / s);
    YP[y1o] = f2bf(e1 / s);
  }

  if (br == 0) {
    float wf0 = x0 + gumbel_f32(g2a, g2b, (u32)i0);
    float wf1 = x1 + gumbel_f32(g2a, g2b, (u32)i1);
    float v1, v2; int i1x;
    if (wf0 >= wf1) { v1 = wf0; i1x = tid; v2 = wf1; }
    else            { v1 = wf1; i1x = tid + 256; v2 = wf0; }
#pragma unroll
    for (int off = 1; off < 64; off <<= 1) {
      float ov1 = __shfl_xor(v1, off, 64);
      int   oi1 = __shfl_xor(i1x, off, 64);
      float ov2 = __shfl_xor(v2, off, 64);
      float n1; int ni;
      if (ov1 > v1 || (ov1 == v1 && oi1 < i1x)) { n1 = ov1; ni = oi1; v2 = fmaxf(v1, ov2); }
      else { n1 = v1; ni = i1x; v2 = fmaxf(v2, ov1 == v1 ? ov2 : ov1); }
      if (ov1 == v1 && oi1 != i1x) v2 = fmaxf(v2, ov1);
      v1 = n1; i1x = ni;
    }
    if (lane == 0) { smV[wid] = v1; smI[wid] = i1x; smV2[wid] = v2; }
    __syncthreads();
    __shared__ int needSlow;
    if (tid == 0) {
      float cv = smV[0]; int ci = smI[0]; float c2 = smV2[0];
#pragma unroll
      for (int t = 1; t < 4; t++) {
        float tv = smV[t]; int ti = smI[t]; float t2 = smV2[t];
        if (tv > cv || (tv == cv && ti < ci)) { c2 = fmaxf(cv, t2); cv = tv; ci = ti; }
        else c2 = fmaxf(c2, tv);
      }
      if (cv - c2 > 5e-5f) { assignOut[b] = (float)ci; needSlow = 0; }
      else needSlow = 1;
    }
    __syncthreads();
    if (needSlow) {
      float w0 = x0 + gumbel_at(g2a, g2b, (u32)i0);
      float w1 = x1 + gumbel_at(g2a, g2b, (u32)i1);
      float wm2 = fmaxf(w0, w1);
#pragma unroll
      for (int off = 1; off < 64; off <<= 1) wm2 = fmaxf(wm2, __shfl_xor(wm2, off, 64));
      if (lane == 0) smM2[wid] = wm2;
      __syncthreads();
      float m2 = fmaxf(fmaxf(smM2[0], smM2[1]), fmaxf(smM2[2], smM2[3]));
      float f0 = expf(w0 - m2), f1 = expf(w1 - m2);
      float ws2 = f0 + f1;
#pragma unroll
      for (int off = 1; off < 64; off <<= 1) ws2 += __shfl_xor(ws2, off, 64);
      if (lane == 0) smS2[wid] = ws2;
      __syncthreads();
      float s2 = (smS2[0] + smS2[1]) + (smS2[2] + smS2[3]);
      float y0 = f0 / s2, y1v = f1 / s2;
      float bv; int bi;
      if (y1v > y0) { bv = y1v; bi = tid + 256; } else { bv = y0; bi = tid; }
#pragma unroll
      for (int off = 1; off < 64; off <<= 1) {
        float ov = __shfl_xor(bv, off, 64);
        int oi = __shfl_xor(bi, off, 64);
        if (ov > bv || (ov == bv && oi < bi)) { bv = ov; bi = oi; }
      }
      if (lane == 0) { smV[wid] = bv; smI[wid] = bi; }
      __syncthreads();
      if (tid == 0) {
        float cv = smV[0]; int ci = smI[0];
#pragma unroll
        for (int t = 1; t < 4; t++) {
          if (smV[t] > cv || (smV[t] == cv && smI[t] < ci)) { cv = smV[t]; ci = smI[t]; }
        }
        assignOut[b] = (float)ci;
      }
    }
  }
}

// ---------------- row sums from packed BIN (count 0x3F80 via bit 7) ----------------
__global__ __launch_bounds__(256)
void k_rowsum(const u16* __restrict__ BINP, float* __restrict__ rs2) {
  __shared__ int sm[256];
  int bid = blockIdx.x, br = bid >> 9, k = bid & 511;
  const u16* base = BINP + ((size_t)(br * 32 + (k >> 4)) * 128) * 512;
  int klane = k & 15;
  int tid = threadIdx.x;
  int cnt = 0;
#pragma unroll
  for (int p = 0; p < 2; p++) {
    int idx = p * 256 + tid;
    int bc = idx >> 2, hi = idx & 3;
    const u16* ptr = base + (size_t)bc * 512 + (klane | (hi << 4)) * 8;
    uint4 v = *(const uint4*)ptr;
    cnt += (int)((v.x >> 7) & 1) + (int)((v.x >> 23) & 1)
         + (int)((v.y >> 7) & 1) + (int)((v.y >> 23) & 1)
         + (int)((v.z >> 7) & 1) + (int)((v.z >> 23) & 1)
         + (int)((v.w >> 7) & 1) + (int)((v.w >> 23) & 1);
  }
  sm[tid] = cnt; __syncthreads();
  for (int off = 128; off > 0; off >>= 1) {
    if (tid < off) sm[tid] += sm[tid + off];
    __syncthreads();
  }
  if (tid == 0) rs2[bid] = (float)sm[0];
}

// ---------------- Taylor-collapsed InfoNCE loss ----------------
__global__ __launch_bounds__(256)
void k_loss_row(const float* __restrict__ QN, const float* __restrict__ KPN,
                const float* __restrict__ QK, const float* __restrict__ KPK,
                const float* __restrict__ csum, const float* __restrict__ lscp,
                float* __restrict__ LPN, float* __restrict__ LPK) {
  __shared__ float pt[4];
  int w = threadIdx.x >> 6, l = threadIdx.x & 63;
  int bid = blockIdx.x;
  int isK = (bid >= 1024);
  int rb = isK ? (bid - 1024) : bid;
  const float* Q  = isK ? QK : QN;
  const float* KP = isK ? KPK : KPN;
  const float* cs4 = csum + (isK ? 256 : 0);
  float Lc = isK ? (float)QQ : (float)LL;
  float lsc = lscp[isK ? 1 : 0];
  int r = rb * 4 + w;
  float4 q = *(const float4*)(Q + (size_t)r * 256 + l * 4);
  float4 kp = *(const float4*)(KP + (size_t)r * 256 + l * 4);
  float4 cs = *(const float4*)(cs4 + l * 4);
  float d1 = q.x * kp.x + q.y * kp.y + q.z * kp.z + q.w * kp.w;
  float d2 = q.x * cs.x + q.y * cs.y + q.z * cs.z + q.w * cs.w;
#pragma unroll
  for (int off = 1; off < 64; off <<= 1) {
    d1 += __shfl_xor(d1, off, 64);
    d2 += __shfl_xor(d2, off, 64);
  }
  if (l == 0) {
    float z0 = d1 / 0.07f;
    double S = (double)Lc + (double)expf(z0) + (double)(lsc * d2);
    pt[w] = (float)(log(S)) - z0;
  }
  __syncthreads();
  if (threadIdx.x == 0) {
    float v = (pt[0] + pt[1]) + (pt[2] + pt[3]);
    if (isK) LPK[rb] = v; else LPN[rb] = v;
  }
}

__global__ __launch_bounds__(256)
void k_loss_final(const float* __restrict__ LPN, int nN, float invMN,
                  const float* __restrict__ LPK, int nK, float invMK,
                  float* __restrict__ outLoss) {
  __shared__ float sm[256];
  int tid = threadIdx.x;
  float a = 0.0f;
  for (int i = tid; i < nN; i += 256) a += LPN[i];
  sm[tid] = a; __syncthreads();
  for (int off = 128; off > 0; off >>= 1) {
    if (tid < off) sm[tid] += sm[tid + off];
    __syncthreads();
  }
  float lossN = sm[0] * invMN;
  __syncthreads();
  float b = 0.0f;
  for (int i = tid; i < nK; i += 256) b += LPK[i];
  sm[tid] = b; __syncthreads();
  for (int off = 128; off > 0; off >>= 1) {
    if (tid < off) sm[tid] += sm[tid + off];
    __syncthreads();
  }
  if (tid == 0) outLoss[0] = lossN + sm[0] * invMK;
}

// ---------------- launch ----------------
extern "C" void kernel_launch(void* const* d_in, const int* in_sizes, int n_in,
                              void* d_out, int out_size, void* d_ws, size_t ws_size,
                              hipStream_t stream) {
  const float* feat0 = (const float*)d_in[0];
  const float* feat1 = (const float*)d_in[1];
  const float* ctx0  = (const float*)d_in[2];
  const float* ctx1  = (const float*)d_in[3];
  const float* queue_n = (const float*)d_in[4];
  const float* queue_k = (const float*)d_in[5];

  float* W = (float*)d_ws;
  size_t o = 0;
  float* T     = W + o; o += 2 * (size_t)BB * KK;
  float* CP    = W + o; o += 32 * (size_t)KK * DD;
  float* CPN   = W + o; o += 4 * (size_t)BB * DD;
  float* AGGN1 = W + o; o += (size_t)BB * DD;
  float* AGGK1 = W + o; o += (size_t)KK * DD;
  float* RS2   = W + o; o += 2 * KK;
  float* CPS   = W + o; o += 2 * 131072;
  float* SQ2   = W + o; o += 2 * 512;
  float* CS    = W + o; o += 2 * 256;
  float* LSC   = W + o; o += 2;
  float* LPN   = W + o; o += 1024;
  float* LPK   = W + o; o += 128;
  float* PART_K = W + o; o += 256;
  float* SQPN  = W + o; o += 2 * 4096;
  float* SQPK  = W + o; o += 2 * 512;
  u16* YP    = (u16*)(W + o); o += (size_t)BB * KK;       // 2*2.1M shorts = 4.2M shorts in 2.1M floats
  u16* BINP  = (u16*)(W + o); o += (size_t)BB * KK;
  u16* featP = (u16*)(W + o); o += (size_t)BB * DD;       // 2*1.05M shorts
  u16* ctxP  = (u16*)(W + o); o += (size_t)KK * DD;       // 2*131K shorts

  float* out = (float*)d_out;
  float* outAssign = out;
  float* outAggn2  = out + BB;
  float* outAggk2  = out + BB + (size_t)BB * DD;
  float* outLoss   = out + BB + (size_t)BB * DD + (size_t)KK * DD;

  u32 kq0, kq1, kc[2][2];
  tf2x32(0u, 42u, 0u, 0u, kq0, kq1);
  tf2x32(0u, 42u, 0u, 1u, kc[0][0], kc[0][1]);
  tf2x32(0u, 42u, 0u, 2u, kc[1][0], kc[1][1]);
  u32 sub[2][3][2];
  for (int br = 0; br < 2; br++)
    for (int t = 0; t < 3; t++)
      tf2x32(kc[br][0], kc[br][1], 0u, (u32)t, sub[br][t][0], sub[br][t][1]);

  // stats chain + operand packing
  k_sumsq<<<256, 256, 0, stream>>>(queue_k, QQ * DD, PART_K);
  k_stats<<<dim3(512, 2), 256, 0, stream>>>(queue_n, queue_k, PART_K, CPS, SQ2, kq0, kq1);
  k_finalize<<<dim3(257, 2), 256, 0, stream>>>(CPS, SQ2, CS, LSC);
  k_pack<<<(2 * BB * DD + 2 * KK * DD) / 256, 256, 0, stream>>>(
      feat0, feat1, ctx0, ctx1, featP, ctxP);

  // branch pipeline
  k_gemm_nt<<<dim3(KK / 64, BB / 64, 2), 256, 0, stream>>>(
      feat0, feat1, ctx0, ctx1, T, BINP,
      sub[0][2][0], sub[0][2][1], sub[1][2][0], sub[1][2][1]);
  k_softmax_assign<<<2 * BB, 256, 0, stream>>>(T, YP, outAssign,
      sub[0][0][0], sub[0][0][1], sub[1][0][0], sub[1][0][1], sub[0][1][0], sub[0][1][1]);
  k_rowsum<<<2 * KK, 256, 0, stream>>>(BINP, RS2);
  k_mfma_aggn<<<dim3(256, 2, 2), 256, 0, stream>>>(YP, ctxP, CPN);
  k_mfma_aggk<<<dim3(32, 16, 2), 256, 0, stream>>>(BINP, featP, CP);
  k_reduce<<<dim3(4608, 2), 256, 0, stream>>>(CPN, CP, RS2, AGGN1, outAggn2,
                                              AGGK1, outAggk2, SQPN, SQPK);
  k_scale<<<dim3(1152, 2), 256, 0, stream>>>(AGGN1, outAggn2, AGGK1, outAggk2, SQPN, SQPK);

  // Taylor-collapsed losses
  k_loss_row<<<1152, 256, 0, stream>>>(AGGN1, outAggn2, AGGK1, outAggk2, CS, LSC, LPN, LPK);
  k_loss_final<<<1, 256, 0, stream>>>(LPN, BB / 4, 1.0f / BB, LPK, KK / 4, 1.0f / KK, outLoss);
}